// Round 6
// baseline (415.593 us; speedup 1.0000x reference)
//
#include <hip/hip_runtime.h>
#include <hip/hip_bf16.h>

#define NN 50000
#define NE 800000
#define DD 128
#define HH 8
#define CC 16
#define DFF 512
#define ED 16
#define SCAN_NB ((NN + 255) / 256)   // 196

typedef __attribute__((ext_vector_type(8))) short bf16x8;
typedef __attribute__((ext_vector_type(4))) float f32x4;

union U8 { bf16x8 v; unsigned short s[8]; };

__device__ inline unsigned short f2bf(float f) {
    union { float f; unsigned u; } v; v.f = f;
    return (unsigned short)((v.u + 0x7fffu + ((v.u >> 16) & 1u)) >> 16);
}
__device__ inline float bf2f(unsigned s) {
    union { unsigned u; float f; } v; v.u = s << 16;
    return v.f;
}

// ---------------- utility ----------------
__global__ void zero_int_k(int* __restrict__ a, int n) {
    int i = blockIdx.x * 256 + threadIdx.x;
    if (i < n) a[i] = 0;
}

// transpose + cvt weights: in [K][Nc] f32 -> out [Nc][K] bf16
__global__ void cvtT_k(const float* __restrict__ in, unsigned short* __restrict__ outT,
                       int K, int Nc) {
    int idx = blockIdx.x * 256 + threadIdx.x;
    if (idx >= K * Nc) return;
    int n = idx / K, k = idx - n * K;
    outT[idx] = f2bf(in[(size_t)k * Nc + n]);
}

// ---------------- CSR build ----------------
__global__ void count_k(const int* __restrict__ dst, int* __restrict__ cnt) {
    int e = blockIdx.x * 256 + threadIdx.x;
    if (e < NE) atomicAdd(&cnt[dst[e]], 1);
}

__global__ void blksum_k(const int* __restrict__ cnt, int* __restrict__ partials) {
    int i = blockIdx.x * 256 + threadIdx.x;
    int v = (i < NN) ? cnt[i] : 0;
#pragma unroll
    for (int m = 1; m < 64; m <<= 1) v += __shfl_xor(v, m, 64);
    __shared__ int ws[4];
    if ((threadIdx.x & 63) == 0) ws[threadIdx.x >> 6] = v;
    __syncthreads();
    if (threadIdx.x == 0) partials[blockIdx.x] = ws[0] + ws[1] + ws[2] + ws[3];
}

__global__ void scanpart_k(int* __restrict__ partials) {
    __shared__ int buf[256];
    int t = threadIdx.x;
    int v = (t < SCAN_NB) ? partials[t] : 0;
    buf[t] = v;
    __syncthreads();
    for (int off = 1; off < 256; off <<= 1) {
        int u = (t >= off) ? buf[t - off] : 0;
        __syncthreads();
        buf[t] += u;
        __syncthreads();
    }
    if (t < SCAN_NB) partials[t] = buf[t] - v;  // exclusive
}

__global__ void scanapply_k(const int* __restrict__ cnt, const int* __restrict__ partials,
                            int* __restrict__ row_start, int* __restrict__ cursor) {
    __shared__ int buf[256];
    int t = threadIdx.x;
    int i = blockIdx.x * 256 + t;
    int v = (i < NN) ? cnt[i] : 0;
    buf[t] = v;
    __syncthreads();
    for (int off = 1; off < 256; off <<= 1) {
        int u = (t >= off) ? buf[t - off] : 0;
        __syncthreads();
        buf[t] += u;
        __syncthreads();
    }
    int excl = buf[t] - v + partials[blockIdx.x];
    if (i < NN) {
        row_start[i] = excl;
        cursor[i] = excl;
        if (i == NN - 1) row_start[NN] = excl + v;
    }
}

__global__ void scatter_k(const int* __restrict__ ei, int* __restrict__ cursor,
                          int* __restrict__ e_src, int* __restrict__ perm) {
    int e = blockIdx.x * 256 + threadIdx.x;
    if (e >= NE) return;
    int s = ei[e];
    int d = ei[NE + e];
    int pos = atomicAdd(&cursor[d], 1);
    e_src[pos] = s;
    perm[e] = pos;
}

// ---------------- edge scores ----------------
__global__ void se_k(const float* __restrict__ ew, const float* __restrict__ We,
                     const float* __restrict__ ae, const int* __restrict__ perm,
                     float* __restrict__ s_e) {
    __shared__ float Ae[ED * HH];
    int t = threadIdx.x;
    if (t < ED * HH) {
        int k = t >> 3, h = t & 7;
        float s = 0.f;
#pragma unroll
        for (int c = 0; c < CC; c++) s += We[k * DD + h * CC + c] * ae[h * CC + c];
        Ae[t] = s;
    }
    __syncthreads();
    int e = blockIdx.x * 256 + t;
    if (e >= NE) return;
    const float* ep = &ew[(size_t)e * ED];
    float4 v0 = *(const float4*)(ep);
    float4 v1 = *(const float4*)(ep + 4);
    float4 v2 = *(const float4*)(ep + 8);
    float4 v3 = *(const float4*)(ep + 12);
    float ev[16] = {v0.x, v0.y, v0.z, v0.w, v1.x, v1.y, v1.z, v1.w,
                    v2.x, v2.y, v2.z, v2.w, v3.x, v3.y, v3.z, v3.w};
    float o[8] = {0, 0, 0, 0, 0, 0, 0, 0};
#pragma unroll
    for (int k = 0; k < 16; k++) {
        float v = ev[k];
#pragma unroll
        for (int h = 0; h < 8; h++) o[h] += v * Ae[k * 8 + h];
    }
    int pp = perm[e];
    *(float4*)&s_e[(size_t)pp * 8]     = make_float4(o[0], o[1], o[2], o[3]);
    *(float4*)&s_e[(size_t)pp * 8 + 4] = make_float4(o[4], o[5], o[6], o[7]);
}

// ---------------- MFMA node GEMM: Ybf = bf16(X @ W) ----------------
__global__ __launch_bounds__(256) void gemm_mfma_k(const float* __restrict__ X,
                                                   const unsigned short* __restrict__ WT,
                                                   unsigned short* __restrict__ Ybf) {
    __shared__ char Xl[128 * 256];  // bf16 [row][128], XOR-swizzled
    int t = threadIdx.x;
    int nb0 = blockIdx.x * 128;
    for (int c = t; c < 2048; c += 256) {
        int row = c >> 4, cb = c & 15;
        int n = nb0 + row;
        U8 u;
        if (n < NN) {
            const float* xp = &X[(size_t)n * DD + cb * 8];
            float4 a = *(const float4*)xp;
            float4 b = *(const float4*)(xp + 4);
            u.s[0] = f2bf(a.x); u.s[1] = f2bf(a.y); u.s[2] = f2bf(a.z); u.s[3] = f2bf(a.w);
            u.s[4] = f2bf(b.x); u.s[5] = f2bf(b.y); u.s[6] = f2bf(b.z); u.s[7] = f2bf(b.w);
        } else {
#pragma unroll
            for (int q = 0; q < 8; q++) u.s[q] = 0;
        }
        int byte = (row * 256 + cb * 16) ^ ((row & 7) << 4);
        *(bf16x8*)&Xl[byte] = u.v;
    }
    __syncthreads();
    int w = t >> 6, l = t & 63;
    int lrow = l & 15, lq = l >> 4;
    int r0 = (w & 1) * 64, c0 = (w >> 1) * 64;
    f32x4 acc[4][4];
#pragma unroll
    for (int i = 0; i < 4; i++)
#pragma unroll
        for (int j = 0; j < 4; j++) acc[i][j] = (f32x4){0.f, 0.f, 0.f, 0.f};
#pragma unroll
    for (int ks = 0; ks < 4; ks++) {
        int k0 = ks * 32;
        bf16x8 af[4], bq[4];
#pragma unroll
        for (int i = 0; i < 4; i++) {
            int rr = r0 + i * 16 + lrow;
            int byte = (rr * 256 + k0 * 2 + lq * 16) ^ ((rr & 7) << 4);
            af[i] = *(const bf16x8*)&Xl[byte];
        }
#pragma unroll
        for (int j = 0; j < 4; j++) {
            int cc = c0 + j * 16 + lrow;
            bq[j] = *(const bf16x8*)&WT[(size_t)cc * DD + k0 + lq * 8];
        }
#pragma unroll
        for (int i = 0; i < 4; i++)
#pragma unroll
            for (int j = 0; j < 4; j++)
                acc[i][j] = __builtin_amdgcn_mfma_f32_16x16x32_bf16(af[i], bq[j], acc[i][j], 0, 0, 0);
    }
#pragma unroll
    for (int i = 0; i < 4; i++) {
#pragma unroll
        for (int j = 0; j < 4; j++) {
#pragma unroll
            for (int q = 0; q < 4; q++) {
                int n = nb0 + r0 + i * 16 + lq * 4 + q;
                if (n < NN) Ybf[(size_t)n * DD + c0 + j * 16 + lrow] = f2bf(acc[i][j][q]);
            }
        }
    }
}

// ---------------- s_src/s_dst from bf16 xh ----------------
__global__ void ssd_k(const unsigned short* __restrict__ xh_bf, const float* __restrict__ a_src,
                      const float* __restrict__ a_dst, float* __restrict__ s_src,
                      float* __restrict__ s_dst) {
    __shared__ float as[128], ad[128];
    if (threadIdx.x < 128) {
        as[threadIdx.x] = a_src[threadIdx.x];
        ad[threadIdx.x] = a_dst[threadIdx.x];
    }
    __syncthreads();
    int idx = blockIdx.x * 256 + threadIdx.x;
    if (idx >= NN * HH) return;
    int n = idx >> 3, h = idx & 7;
    const unsigned short* x = &xh_bf[(size_t)n * DD + h * CC];
    U8 u0, u1;
    u0.v = *(const bf16x8*)(x);
    u1.v = *(const bf16x8*)(x + 8);
    float s1 = 0.f, s2 = 0.f;
#pragma unroll
    for (int c = 0; c < 8; c++) {
        float v = bf2f(u0.s[c]);
        s1 += v * as[h * CC + c];
        s2 += v * ad[h * CC + c];
    }
#pragma unroll
    for (int c = 0; c < 8; c++) {
        float v = bf2f(u1.s[c]);
        s1 += v * as[h * CC + 8 + c];
        s2 += v * ad[h * CC + 8 + c];
    }
    s_src[idx] = s1;
    s_dst[idx] = s2;
}

// ---------------- aggregation: one wave per destination node, bf16 gather, unroll-2 ----------------
__global__ __launch_bounds__(256) void agg_k(const int* __restrict__ row_start,
                                             const int* __restrict__ e_src,
                                             const float* __restrict__ s_src,
                                             const float* __restrict__ s_dst,
                                             const float* __restrict__ s_e,
                                             const unsigned short* __restrict__ xh_bf,
                                             float* __restrict__ out) {
    int wid = (blockIdx.x * 256 + threadIdx.x) >> 6;
    if (wid >= NN) return;
    int lane = threadIdx.x & 63;
    int h = lane >> 3;
    float sdst = s_dst[wid * 8 + h];
    int beg = row_start[wid], end = row_start[wid + 1];
    float acc0 = 0.f, acc1 = 0.f, z = 0.f;
    int p = beg;
    for (; p + 2 <= end; p += 2) {
        int s0 = e_src[p];
        int s1 = e_src[p + 1];
        float a0 = s_src[s0 * 8 + h] + sdst + s_e[(size_t)p * 8 + h];
        float a1 = s_src[s1 * 8 + h] + sdst + s_e[(size_t)(p + 1) * 8 + h];
        unsigned u0 = *(const unsigned*)&xh_bf[(size_t)s0 * DD + lane * 2];
        unsigned u1 = *(const unsigned*)&xh_bf[(size_t)s1 * DD + lane * 2];
        a0 = (a0 > 0.f) ? a0 : 0.2f * a0;
        a1 = (a1 > 0.f) ? a1 : 0.2f * a1;
        float e0 = __expf(a0);
        float e1 = __expf(a1);
        z += e0 + e1;
        acc0 = fmaf(e0, bf2f(u0 & 0xffffu), acc0);
        acc1 = fmaf(e0, bf2f(u0 >> 16), acc1);
        acc0 = fmaf(e1, bf2f(u1 & 0xffffu), acc0);
        acc1 = fmaf(e1, bf2f(u1 >> 16), acc1);
    }
    if (p < end) {
        int s0 = e_src[p];
        float a0 = s_src[s0 * 8 + h] + sdst + s_e[(size_t)p * 8 + h];
        unsigned u0 = *(const unsigned*)&xh_bf[(size_t)s0 * DD + lane * 2];
        a0 = (a0 > 0.f) ? a0 : 0.2f * a0;
        float e0 = __expf(a0);
        z += e0;
        acc0 = fmaf(e0, bf2f(u0 & 0xffffu), acc0);
        acc1 = fmaf(e0, bf2f(u0 >> 16), acc1);
    }
    float inv = 1.f / (z + 1e-16f);
    *(float2*)&out[(size_t)wid * DD + lane * 2] = make_float2(acc0 * inv, acc1 * inv);
}

// ---------------- bias + LayerNorm(ddof=1) + leaky_relu + residual ----------------
__global__ __launch_bounds__(256) void ln_k(const float* __restrict__ hin,
                                            const float* __restrict__ bias,
                                            const float* __restrict__ g,
                                            const float* __restrict__ be,
                                            const float* __restrict__ res,
                                            float* __restrict__ out) {
    int wid = (blockIdx.x * 256 + threadIdx.x) >> 6;
    if (wid >= NN) return;
    int lane = threadIdx.x & 63;
    float2 x = *(const float2*)&hin[(size_t)wid * DD + lane * 2];
    float2 b = *(const float2*)&bias[lane * 2];
    x.x += b.x;
    x.y += b.y;
    float s = x.x + x.y;
    float q = x.x * x.x + x.y * x.y;
#pragma unroll
    for (int m = 1; m < 64; m <<= 1) {
        s += __shfl_xor(s, m, 64);
        q += __shfl_xor(q, m, 64);
    }
    float mu = s * (1.f / 128.f);
    float var = (q - 128.f * mu * mu) * (1.f / 127.f);
    float sd = sqrtf(fmaxf(var, 0.f));
    float inv = 1.f / (sd + 1e-6f);
    float2 gg = *(const float2*)&g[lane * 2];
    float2 bb = *(const float2*)&be[lane * 2];
    float y0 = gg.x * (x.x - mu) * inv + bb.x;
    float y1 = gg.y * (x.y - mu) * inv + bb.y;
    y0 = (y0 > 0.f) ? y0 : 0.01f * y0;
    y1 = (y1 > 0.f) ? y1 : 0.01f * y1;
    float2 r = *(const float2*)&res[(size_t)wid * DD + lane * 2];
    *(float2*)&out[(size_t)wid * DD + lane * 2] = make_float2(r.x + y0, r.y + y1);
}

// ---------------- fused MFMA FFN: 64 nodes/block, hidden in 4 chunks of 128 ----------------
// per chunk: phase A  S = relu(X@Wf1[:,chunk]+b) -> Hl (bf16, swizzled LDS)
//            phase B  oacc += Hl @ Wf2[chunk,:]
__global__ __launch_bounds__(256) void ffn_mfma_k(const float* __restrict__ X,
                                                  const unsigned short* __restrict__ Wf1T,
                                                  const float* __restrict__ bf1,
                                                  const unsigned short* __restrict__ Wf2T,
                                                  float* __restrict__ out) {
    __shared__ char Xl[64 * 256];   // bf16 [64][128] swizzled, 16KB
    __shared__ char Hl[64 * 256];   // bf16 [64][128] swizzled, 16KB
    int t = threadIdx.x;
    int nb0 = blockIdx.x * 64;
    for (int c = t; c < 1024; c += 256) {
        int row = c >> 4, cb = c & 15;
        int n = nb0 + row;
        U8 u;
        if (n < NN) {
            const float* xp = &X[(size_t)n * DD + cb * 8];
            float4 a = *(const float4*)xp;
            float4 b = *(const float4*)(xp + 4);
            u.s[0] = f2bf(a.x); u.s[1] = f2bf(a.y); u.s[2] = f2bf(a.z); u.s[3] = f2bf(a.w);
            u.s[4] = f2bf(b.x); u.s[5] = f2bf(b.y); u.s[6] = f2bf(b.z); u.s[7] = f2bf(b.w);
        } else {
#pragma unroll
            for (int q = 0; q < 8; q++) u.s[q] = 0;
        }
        int byte = (row * 256 + cb * 16) ^ ((row & 7) << 4);
        *(bf16x8*)&Xl[byte] = u.v;
    }
    __syncthreads();
    int w = t >> 6, l = t & 63;
    int lrow = l & 15, lq = l >> 4;
    int wr = (w & 1) * 32;   // wave's node-row base (32 rows)
    int wc = (w >> 1) * 64;  // wave's col base (64 cols of 128)
    f32x4 oacc[2][4];
#pragma unroll
    for (int i = 0; i < 2; i++)
#pragma unroll
        for (int j = 0; j < 4; j++) oacc[i][j] = (f32x4){0.f, 0.f, 0.f, 0.f};

#pragma unroll
    for (int ch = 0; ch < 4; ch++) {
        int hc0 = ch * 128;
        // ---- phase A: S-chunk ----
        f32x4 a[2][4];
#pragma unroll
        for (int i = 0; i < 2; i++)
#pragma unroll
            for (int j = 0; j < 4; j++) a[i][j] = (f32x4){0.f, 0.f, 0.f, 0.f};
#pragma unroll
        for (int ks = 0; ks < 4; ks++) {
            int k0 = ks * 32;
            bf16x8 af[2], bq[4];
#pragma unroll
            for (int i = 0; i < 2; i++) {
                int rr = wr + i * 16 + lrow;
                int byte = (rr * 256 + k0 * 2 + lq * 16) ^ ((rr & 7) << 4);
                af[i] = *(const bf16x8*)&Xl[byte];
            }
#pragma unroll
            for (int j = 0; j < 4; j++) {
                int cc = hc0 + wc + j * 16 + lrow;
                bq[j] = *(const bf16x8*)&Wf1T[(size_t)cc * DD + k0 + lq * 8];
            }
#pragma unroll
            for (int i = 0; i < 2; i++)
#pragma unroll
                for (int j = 0; j < 4; j++)
                    a[i][j] = __builtin_amdgcn_mfma_f32_16x16x32_bf16(af[i], bq[j], a[i][j], 0, 0, 0);
        }
        float bias[4];
#pragma unroll
        for (int j = 0; j < 4; j++) bias[j] = bf1[hc0 + wc + j * 16 + lrow];
#pragma unroll
        for (int i = 0; i < 2; i++) {
#pragma unroll
            for (int j = 0; j < 4; j++) {
#pragma unroll
                for (int q = 0; q < 4; q++) {
                    float v = fmaxf(a[i][j][q] + bias[j], 0.f);
                    int row = wr + i * 16 + lq * 4 + q;
                    int col = wc + j * 16 + lrow;
                    int byte = (row * 256 + col * 2) ^ ((row & 7) << 4);
                    *(unsigned short*)&Hl[byte] = f2bf(v);
                }
            }
        }
        __syncthreads();
        // ---- phase B: accumulate out ----
#pragma unroll
        for (int ks = 0; ks < 4; ks++) {
            int k0 = ks * 32;
            bf16x8 hf[2], b2[4];
#pragma unroll
            for (int i = 0; i < 2; i++) {
                int rr = wr + i * 16 + lrow;
                int byte = (rr * 256 + k0 * 2 + lq * 16) ^ ((rr & 7) << 4);
                hf[i] = *(const bf16x8*)&Hl[byte];
            }
#pragma unroll
            for (int j = 0; j < 4; j++) {
                int cc = wc + j * 16 + lrow;
                b2[j] = *(const bf16x8*)&Wf2T[(size_t)cc * DFF + hc0 + k0 + lq * 8];
            }
#pragma unroll
            for (int i = 0; i < 2; i++)
#pragma unroll
                for (int j = 0; j < 4; j++)
                    oacc[i][j] = __builtin_amdgcn_mfma_f32_16x16x32_bf16(hf[i], b2[j], oacc[i][j], 0, 0, 0);
        }
        __syncthreads();
    }
#pragma unroll
    for (int i = 0; i < 2; i++) {
#pragma unroll
        for (int j = 0; j < 4; j++) {
#pragma unroll
            for (int q = 0; q < 4; q++) {
                int n = nb0 + wr + i * 16 + lq * 4 + q;
                if (n < NN) out[(size_t)n * DD + wc + j * 16 + lrow] = oacc[i][j][q];
            }
        }
    }
}

extern "C" void kernel_launch(void* const* d_in, const int* in_sizes, int n_in,
                              void* d_out, int out_size, void* d_ws, size_t ws_size,
                              hipStream_t stream) {
    const float* nf  = (const float*)d_in[0];
    const int*   ei  = (const int*)d_in[1];
    const float* ew  = (const float*)d_in[2];
    const float* W1  = (const float*)d_in[3];
    const float* as1 = (const float*)d_in[4];
    const float* ad1 = (const float*)d_in[5];
    const float* We1 = (const float*)d_in[6];
    const float* ae1 = (const float*)d_in[7];
    const float* b1  = (const float*)d_in[8];
    const float* g1  = (const float*)d_in[9];
    const float* be1 = (const float*)d_in[10];
    const float* W2  = (const float*)d_in[11];
    const float* as2 = (const float*)d_in[12];
    const float* ad2 = (const float*)d_in[13];
    const float* We2 = (const float*)d_in[14];
    const float* ae2 = (const float*)d_in[15];
    const float* b2  = (const float*)d_in[16];
    const float* g2  = (const float*)d_in[17];
    const float* be2 = (const float*)d_in[18];
    const float* Wf1 = (const float*)d_in[19];
    const float* bf1 = (const float*)d_in[20];
    const float* Wf2 = (const float*)d_in[21];
    const float* bf2 = (const float*)d_in[22];
    const float* g3  = (const float*)d_in[23];
    const float* be3 = (const float*)d_in[24];
    float* out = (float*)d_out;

    char* p = (char*)d_ws;
    auto alloc = [&](size_t bytes) {
        char* r = p;
        p += (bytes + 255) & ~(size_t)255;
        return r;
    };
    float* nf_cur = (float*)alloc((size_t)NN * DD * 4);
    float* h_out  = (float*)alloc((size_t)NN * DD * 4);
    unsigned short* xh_bf = (unsigned short*)alloc((size_t)NN * DD * 2);
    float* s_e    = (float*)alloc((size_t)NE * HH * 4);
    float* s_src  = (float*)alloc((size_t)NN * HH * 4);
    float* s_dst  = (float*)alloc((size_t)NN * HH * 4);
    int* row_start = (int*)alloc((size_t)(NN + 1) * 4);
    int* cnt       = (int*)alloc((size_t)NN * 4);
    int* cursor    = (int*)alloc((size_t)NN * 4);
    int* partials  = (int*)alloc((size_t)SCAN_NB * 4);
    int* e_src     = (int*)alloc((size_t)NE * 4);
    int* perm      = (int*)alloc((size_t)NE * 4);
    unsigned short* W1T  = (unsigned short*)alloc((size_t)DD * DD * 2);
    unsigned short* W2T  = (unsigned short*)alloc((size_t)DD * DD * 2);
    unsigned short* Wf1T = (unsigned short*)alloc((size_t)DFF * DD * 2);
    unsigned short* Wf2T = (unsigned short*)alloc((size_t)DD * DFF * 2);

    int ebl = (NE + 255) / 256;
    int nbl = (NN + 255) / 256;

    // weight transpose+cvt (tiny, once)
    cvtT_k<<<(DD * DD + 255) / 256, 256, 0, stream>>>(W1, W1T, DD, DD);
    cvtT_k<<<(DD * DD + 255) / 256, 256, 0, stream>>>(W2, W2T, DD, DD);
    cvtT_k<<<(DD * DFF + 255) / 256, 256, 0, stream>>>(Wf1, Wf1T, DD, DFF);   // [512][128]
    cvtT_k<<<(DD * DFF + 255) / 256, 256, 0, stream>>>(Wf2, Wf2T, DFF, DD);   // [128][512]

    // CSR build (hierarchical scan)
    zero_int_k<<<nbl, 256, 0, stream>>>(cnt, NN);
    count_k<<<ebl, 256, 0, stream>>>(ei + NE, cnt);
    blksum_k<<<SCAN_NB, 256, 0, stream>>>(cnt, partials);
    scanpart_k<<<1, 256, 0, stream>>>(partials);
    scanapply_k<<<SCAN_NB, 256, 0, stream>>>(cnt, partials, row_start, cursor);
    scatter_k<<<ebl, 256, 0, stream>>>(ei, cursor, e_src, perm);

    int gbl = (NN + 127) / 128;
    int wbl = (NN + 3) / 4;
    int sbl = (NN * HH + 255) / 256;

    // ---- GAT layer 1 ----
    se_k<<<ebl, 256, 0, stream>>>(ew, We1, ae1, perm, s_e);
    gemm_mfma_k<<<gbl, 256, 0, stream>>>(nf, W1T, xh_bf);
    ssd_k<<<sbl, 256, 0, stream>>>(xh_bf, as1, ad1, s_src, s_dst);
    agg_k<<<wbl, 256, 0, stream>>>(row_start, e_src, s_src, s_dst, s_e, xh_bf, h_out);
    ln_k<<<wbl, 256, 0, stream>>>(h_out, b1, g1, be1, nf, nf_cur);

    // ---- GAT layer 2 ----
    se_k<<<ebl, 256, 0, stream>>>(ew, We2, ae2, perm, s_e);
    gemm_mfma_k<<<gbl, 256, 0, stream>>>(nf_cur, W2T, xh_bf);
    ssd_k<<<sbl, 256, 0, stream>>>(xh_bf, as2, ad2, s_src, s_dst);
    agg_k<<<wbl, 256, 0, stream>>>(row_start, e_src, s_src, s_dst, s_e, xh_bf, h_out);
    ln_k<<<wbl, 256, 0, stream>>>(h_out, b2, g2, be2, nf_cur, nf_cur);

    // ---- FFN ----
    ffn_mfma_k<<<(NN + 63) / 64, 256, 0, stream>>>(nf_cur, Wf1T, bf1, Wf2T, h_out);
    ln_k<<<wbl, 256, 0, stream>>>(h_out, bf2, g3, be3, nf_cur, out);
}

// Round 7
// 373.349 us; speedup vs baseline: 1.1131x; 1.1131x over previous
//
#include <hip/hip_runtime.h>
#include <hip/hip_bf16.h>

#define NN 50000
#define NE 800000
#define DD 128
#define HH 8
#define CC 16
#define DFF 512
#define ED 16
#define SCAN_NB ((NN + 255) / 256)   // 196

typedef __attribute__((ext_vector_type(8))) short bf16x8;
typedef __attribute__((ext_vector_type(4))) float f32x4;

union U8 { bf16x8 v; unsigned short s[8]; };

__device__ inline unsigned short f2bf(float f) {
    union { float f; unsigned u; } v; v.f = f;
    return (unsigned short)((v.u + 0x7fffu + ((v.u >> 16) & 1u)) >> 16);
}
__device__ inline float bf2f(unsigned s) {
    union { unsigned u; float f; } v; v.u = s << 16;
    return v.f;
}

// ---------------- utility ----------------
__global__ void zero_int_k(int* __restrict__ a, int n) {
    int i = blockIdx.x * 256 + threadIdx.x;
    if (i < n) a[i] = 0;
}

// pack weights into MFMA B-fragment order:
// Wpk[((kt*(N/16)+jc)*64 + l)*8 + e] = bf16( W[kt*32+(l>>4)*8+e][jc*16+(l&15)] )
__global__ void cvtpack_k(const float* __restrict__ W, unsigned short* __restrict__ Wpk,
                          int K, int N) {
    int idx = blockIdx.x * 256 + threadIdx.x;
    if (idx >= K * N) return;
    int e = idx & 7;
    int l = (idx >> 3) & 63;
    int r = idx >> 9;
    int n16 = N >> 4;
    int jc = r % n16;
    int kt = r / n16;
    int k = kt * 32 + (l >> 4) * 8 + e;
    int n = jc * 16 + (l & 15);
    Wpk[idx] = f2bf(W[(size_t)k * N + n]);
}

// ---------------- CSR build ----------------
__global__ void count_k(const int* __restrict__ dst, int* __restrict__ cnt) {
    int e = blockIdx.x * 256 + threadIdx.x;
    if (e < NE) atomicAdd(&cnt[dst[e]], 1);
}

__global__ void blksum_k(const int* __restrict__ cnt, int* __restrict__ partials) {
    int i = blockIdx.x * 256 + threadIdx.x;
    int v = (i < NN) ? cnt[i] : 0;
#pragma unroll
    for (int m = 1; m < 64; m <<= 1) v += __shfl_xor(v, m, 64);
    __shared__ int ws[4];
    if ((threadIdx.x & 63) == 0) ws[threadIdx.x >> 6] = v;
    __syncthreads();
    if (threadIdx.x == 0) partials[blockIdx.x] = ws[0] + ws[1] + ws[2] + ws[3];
}

__global__ void scanpart_k(int* __restrict__ partials) {
    __shared__ int buf[256];
    int t = threadIdx.x;
    int v = (t < SCAN_NB) ? partials[t] : 0;
    buf[t] = v;
    __syncthreads();
    for (int off = 1; off < 256; off <<= 1) {
        int u = (t >= off) ? buf[t - off] : 0;
        __syncthreads();
        buf[t] += u;
        __syncthreads();
    }
    if (t < SCAN_NB) partials[t] = buf[t] - v;  // exclusive
}

__global__ void scanapply_k(const int* __restrict__ cnt, const int* __restrict__ partials,
                            int* __restrict__ row_start, int* __restrict__ cursor) {
    __shared__ int buf[256];
    int t = threadIdx.x;
    int i = blockIdx.x * 256 + t;
    int v = (i < NN) ? cnt[i] : 0;
    buf[t] = v;
    __syncthreads();
    for (int off = 1; off < 256; off <<= 1) {
        int u = (t >= off) ? buf[t - off] : 0;
        __syncthreads();
        buf[t] += u;
        __syncthreads();
    }
    int excl = buf[t] - v + partials[blockIdx.x];
    if (i < NN) {
        row_start[i] = excl;
        cursor[i] = excl;
        if (i == NN - 1) row_start[NN] = excl + v;
    }
}

__global__ void scatter_k(const int* __restrict__ ei, int* __restrict__ cursor,
                          int* __restrict__ e_src, int* __restrict__ perm) {
    int e = blockIdx.x * 256 + threadIdx.x;
    if (e >= NE) return;
    int s = ei[e];
    int d = ei[NE + e];
    int pos = atomicAdd(&cursor[d], 1);
    e_src[pos] = s;
    perm[e] = pos;
}

// ---------------- edge scores ----------------
__global__ void se_k(const float* __restrict__ ew, const float* __restrict__ We,
                     const float* __restrict__ ae, const int* __restrict__ perm,
                     float* __restrict__ s_e) {
    __shared__ float Ae[ED * HH];
    int t = threadIdx.x;
    if (t < ED * HH) {
        int k = t >> 3, h = t & 7;
        float s = 0.f;
#pragma unroll
        for (int c = 0; c < CC; c++) s += We[k * DD + h * CC + c] * ae[h * CC + c];
        Ae[t] = s;
    }
    __syncthreads();
    int e = blockIdx.x * 256 + t;
    if (e >= NE) return;
    const float* ep = &ew[(size_t)e * ED];
    float4 v0 = *(const float4*)(ep);
    float4 v1 = *(const float4*)(ep + 4);
    float4 v2 = *(const float4*)(ep + 8);
    float4 v3 = *(const float4*)(ep + 12);
    float ev[16] = {v0.x, v0.y, v0.z, v0.w, v1.x, v1.y, v1.z, v1.w,
                    v2.x, v2.y, v2.z, v2.w, v3.x, v3.y, v3.z, v3.w};
    float o[8] = {0, 0, 0, 0, 0, 0, 0, 0};
#pragma unroll
    for (int k = 0; k < 16; k++) {
        float v = ev[k];
#pragma unroll
        for (int h = 0; h < 8; h++) o[h] += v * Ae[k * 8 + h];
    }
    int pp = perm[e];
    *(float4*)&s_e[(size_t)pp * 8]     = make_float4(o[0], o[1], o[2], o[3]);
    *(float4*)&s_e[(size_t)pp * 8 + 4] = make_float4(o[4], o[5], o[6], o[7]);
}

// ---------------- MFMA node GEMM: Ybf = bf16(X @ W), W packed in fragment order ----------------
__global__ __launch_bounds__(256) void gemm_mfma_k(const float* __restrict__ X,
                                                   const unsigned short* __restrict__ Wpk,
                                                   unsigned short* __restrict__ Ybf) {
    __shared__ char Xl[128 * 256];  // bf16 [row][128], XOR-swizzled
    int t = threadIdx.x;
    int nb0 = blockIdx.x * 128;
    for (int c = t; c < 2048; c += 256) {
        int row = c >> 4, cb = c & 15;
        int n = nb0 + row;
        U8 u;
        if (n < NN) {
            const float* xp = &X[(size_t)n * DD + cb * 8];
            float4 a = *(const float4*)xp;
            float4 b = *(const float4*)(xp + 4);
            u.s[0] = f2bf(a.x); u.s[1] = f2bf(a.y); u.s[2] = f2bf(a.z); u.s[3] = f2bf(a.w);
            u.s[4] = f2bf(b.x); u.s[5] = f2bf(b.y); u.s[6] = f2bf(b.z); u.s[7] = f2bf(b.w);
        } else {
#pragma unroll
            for (int q = 0; q < 8; q++) u.s[q] = 0;
        }
        int byte = (row * 256 + cb * 16) ^ ((row & 7) << 4);
        *(bf16x8*)&Xl[byte] = u.v;
    }
    __syncthreads();
    int w = t >> 6, l = t & 63;
    int lrow = l & 15, lq = l >> 4;
    int r0 = (w & 1) * 64, c0 = (w >> 1) * 64;
    f32x4 acc[4][4];
#pragma unroll
    for (int i = 0; i < 4; i++)
#pragma unroll
        for (int j = 0; j < 4; j++) acc[i][j] = (f32x4){0.f, 0.f, 0.f, 0.f};
#pragma unroll
    for (int ks = 0; ks < 4; ks++) {
        int k0 = ks * 32;
        bf16x8 af[4], bq[4];
#pragma unroll
        for (int i = 0; i < 4; i++) {
            int rr = r0 + i * 16 + lrow;
            int byte = (rr * 256 + k0 * 2 + lq * 16) ^ ((rr & 7) << 4);
            af[i] = *(const bf16x8*)&Xl[byte];
        }
#pragma unroll
        for (int j = 0; j < 4; j++) {
            int j16 = (c0 >> 4) + j;
            bq[j] = *(const bf16x8*)&Wpk[(((size_t)ks * 8 + j16) * 64 + l) * 8];
        }
#pragma unroll
        for (int i = 0; i < 4; i++)
#pragma unroll
            for (int j = 0; j < 4; j++)
                acc[i][j] = __builtin_amdgcn_mfma_f32_16x16x32_bf16(af[i], bq[j], acc[i][j], 0, 0, 0);
    }
#pragma unroll
    for (int i = 0; i < 4; i++) {
#pragma unroll
        for (int j = 0; j < 4; j++) {
#pragma unroll
            for (int q = 0; q < 4; q++) {
                int n = nb0 + r0 + i * 16 + lq * 4 + q;
                if (n < NN) Ybf[(size_t)n * DD + c0 + j * 16 + lrow] = f2bf(acc[i][j][q]);
            }
        }
    }
}

// ---------------- s_src/s_dst from bf16 xh ----------------
__global__ void ssd_k(const unsigned short* __restrict__ xh_bf, const float* __restrict__ a_src,
                      const float* __restrict__ a_dst, float* __restrict__ s_src,
                      float* __restrict__ s_dst) {
    __shared__ float as[128], ad[128];
    if (threadIdx.x < 128) {
        as[threadIdx.x] = a_src[threadIdx.x];
        ad[threadIdx.x] = a_dst[threadIdx.x];
    }
    __syncthreads();
    int idx = blockIdx.x * 256 + threadIdx.x;
    if (idx >= NN * HH) return;
    int n = idx >> 3, h = idx & 7;
    const unsigned short* x = &xh_bf[(size_t)n * DD + h * CC];
    U8 u0, u1;
    u0.v = *(const bf16x8*)(x);
    u1.v = *(const bf16x8*)(x + 8);
    float s1 = 0.f, s2 = 0.f;
#pragma unroll
    for (int c = 0; c < 8; c++) {
        float v = bf2f(u0.s[c]);
        s1 += v * as[h * CC + c];
        s2 += v * ad[h * CC + c];
    }
#pragma unroll
    for (int c = 0; c < 8; c++) {
        float v = bf2f(u1.s[c]);
        s1 += v * as[h * CC + 8 + c];
        s2 += v * ad[h * CC + 8 + c];
    }
    s_src[idx] = s1;
    s_dst[idx] = s2;
}

// ---------------- aggregation: one wave per destination node, bf16 gather, unroll-2 ----------------
__global__ __launch_bounds__(256) void agg_k(const int* __restrict__ row_start,
                                             const int* __restrict__ e_src,
                                             const float* __restrict__ s_src,
                                             const float* __restrict__ s_dst,
                                             const float* __restrict__ s_e,
                                             const unsigned short* __restrict__ xh_bf,
                                             float* __restrict__ out) {
    int wid = (blockIdx.x * 256 + threadIdx.x) >> 6;
    if (wid >= NN) return;
    int lane = threadIdx.x & 63;
    int h = lane >> 3;
    float sdst = s_dst[wid * 8 + h];
    int beg = row_start[wid], end = row_start[wid + 1];
    float acc0 = 0.f, acc1 = 0.f, z = 0.f;
    int p = beg;
    for (; p + 2 <= end; p += 2) {
        int s0 = e_src[p];
        int s1 = e_src[p + 1];
        float a0 = s_src[s0 * 8 + h] + sdst + s_e[(size_t)p * 8 + h];
        float a1 = s_src[s1 * 8 + h] + sdst + s_e[(size_t)(p + 1) * 8 + h];
        unsigned u0 = *(const unsigned*)&xh_bf[(size_t)s0 * DD + lane * 2];
        unsigned u1 = *(const unsigned*)&xh_bf[(size_t)s1 * DD + lane * 2];
        a0 = (a0 > 0.f) ? a0 : 0.2f * a0;
        a1 = (a1 > 0.f) ? a1 : 0.2f * a1;
        float e0 = __expf(a0);
        float e1 = __expf(a1);
        z += e0 + e1;
        acc0 = fmaf(e0, bf2f(u0 & 0xffffu), acc0);
        acc1 = fmaf(e0, bf2f(u0 >> 16), acc1);
        acc0 = fmaf(e1, bf2f(u1 & 0xffffu), acc0);
        acc1 = fmaf(e1, bf2f(u1 >> 16), acc1);
    }
    if (p < end) {
        int s0 = e_src[p];
        float a0 = s_src[s0 * 8 + h] + sdst + s_e[(size_t)p * 8 + h];
        unsigned u0 = *(const unsigned*)&xh_bf[(size_t)s0 * DD + lane * 2];
        a0 = (a0 > 0.f) ? a0 : 0.2f * a0;
        float e0 = __expf(a0);
        z += e0;
        acc0 = fmaf(e0, bf2f(u0 & 0xffffu), acc0);
        acc1 = fmaf(e0, bf2f(u0 >> 16), acc1);
    }
    float inv = 1.f / (z + 1e-16f);
    *(float2*)&out[(size_t)wid * DD + lane * 2] = make_float2(acc0 * inv, acc1 * inv);
}

// ---------------- bias + LayerNorm(ddof=1) + leaky_relu + residual ----------------
__global__ __launch_bounds__(256) void ln_k(const float* __restrict__ hin,
                                            const float* __restrict__ bias,
                                            const float* __restrict__ g,
                                            const float* __restrict__ be,
                                            const float* __restrict__ res,
                                            float* __restrict__ out) {
    int wid = (blockIdx.x * 256 + threadIdx.x) >> 6;
    if (wid >= NN) return;
    int lane = threadIdx.x & 63;
    float2 x = *(const float2*)&hin[(size_t)wid * DD + lane * 2];
    float2 b = *(const float2*)&bias[lane * 2];
    x.x += b.x;
    x.y += b.y;
    float s = x.x + x.y;
    float q = x.x * x.x + x.y * x.y;
#pragma unroll
    for (int m = 1; m < 64; m <<= 1) {
        s += __shfl_xor(s, m, 64);
        q += __shfl_xor(q, m, 64);
    }
    float mu = s * (1.f / 128.f);
    float var = (q - 128.f * mu * mu) * (1.f / 127.f);
    float sd = sqrtf(fmaxf(var, 0.f));
    float inv = 1.f / (sd + 1e-6f);
    float2 gg = *(const float2*)&g[lane * 2];
    float2 bb = *(const float2*)&be[lane * 2];
    float y0 = gg.x * (x.x - mu) * inv + bb.x;
    float y1 = gg.y * (x.y - mu) * inv + bb.y;
    y0 = (y0 > 0.f) ? y0 : 0.01f * y0;
    y1 = (y1 > 0.f) ? y1 : 0.01f * y1;
    float2 r = *(const float2*)&res[(size_t)wid * DD + lane * 2];
    *(float2*)&out[(size_t)wid * DD + lane * 2] = make_float2(r.x + y0, r.y + y1);
}

// ---------------- fused MFMA FFN: 64 nodes/block, hidden in 4 chunks of 128 ----------------
// weights pre-packed in fragment order (perfectly coalesced loads)
__global__ __launch_bounds__(256) void ffn_mfma_k(const float* __restrict__ X,
                                                  const unsigned short* __restrict__ Wf1pk,
                                                  const float* __restrict__ bf1,
                                                  const unsigned short* __restrict__ Wf2pk,
                                                  float* __restrict__ out) {
    __shared__ char Xl[64 * 256];   // bf16 [64][128] swizzled, 16KB
    __shared__ char Hl[64 * 256];   // bf16 [64][128] swizzled, 16KB
    int t = threadIdx.x;
    int nb0 = blockIdx.x * 64;
    for (int c = t; c < 1024; c += 256) {
        int row = c >> 4, cb = c & 15;
        int n = nb0 + row;
        U8 u;
        if (n < NN) {
            const float* xp = &X[(size_t)n * DD + cb * 8];
            float4 a = *(const float4*)xp;
            float4 b = *(const float4*)(xp + 4);
            u.s[0] = f2bf(a.x); u.s[1] = f2bf(a.y); u.s[2] = f2bf(a.z); u.s[3] = f2bf(a.w);
            u.s[4] = f2bf(b.x); u.s[5] = f2bf(b.y); u.s[6] = f2bf(b.z); u.s[7] = f2bf(b.w);
        } else {
#pragma unroll
            for (int q = 0; q < 8; q++) u.s[q] = 0;
        }
        int byte = (row * 256 + cb * 16) ^ ((row & 7) << 4);
        *(bf16x8*)&Xl[byte] = u.v;
    }
    __syncthreads();
    int w = t >> 6, l = t & 63;
    int lrow = l & 15, lq = l >> 4;
    int wr = (w & 1) * 32;   // wave's node-row base (32 rows)
    int wc = (w >> 1) * 64;  // wave's col base (64 cols of 128)
    f32x4 oacc[2][4];
#pragma unroll
    for (int i = 0; i < 2; i++)
#pragma unroll
        for (int j = 0; j < 4; j++) oacc[i][j] = (f32x4){0.f, 0.f, 0.f, 0.f};

#pragma unroll
    for (int ch = 0; ch < 4; ch++) {
        int hc0 = ch * 128;
        // ---- phase A: S-chunk = relu(X @ Wf1[:,chunk] + b) ----
        f32x4 a[2][4];
#pragma unroll
        for (int i = 0; i < 2; i++)
#pragma unroll
            for (int j = 0; j < 4; j++) a[i][j] = (f32x4){0.f, 0.f, 0.f, 0.f};
#pragma unroll
        for (int ks = 0; ks < 4; ks++) {
            int k0 = ks * 32;
            bf16x8 af[2], bq[4];
#pragma unroll
            for (int i = 0; i < 2; i++) {
                int rr = wr + i * 16 + lrow;
                int byte = (rr * 256 + k0 * 2 + lq * 16) ^ ((rr & 7) << 4);
                af[i] = *(const bf16x8*)&Xl[byte];
            }
#pragma unroll
            for (int j = 0; j < 4; j++) {
                int j16 = ch * 8 + (wc >> 4) + j;   // abs 16-col tile in [0,32)
                bq[j] = *(const bf16x8*)&Wf1pk[(((size_t)ks * 32 + j16) * 64 + l) * 8];
            }
#pragma unroll
            for (int i = 0; i < 2; i++)
#pragma unroll
                for (int j = 0; j < 4; j++)
                    a[i][j] = __builtin_amdgcn_mfma_f32_16x16x32_bf16(af[i], bq[j], a[i][j], 0, 0, 0);
        }
        float bias[4];
#pragma unroll
        for (int j = 0; j < 4; j++) bias[j] = bf1[hc0 + wc + j * 16 + lrow];
#pragma unroll
        for (int i = 0; i < 2; i++) {
#pragma unroll
            for (int j = 0; j < 4; j++) {
#pragma unroll
                for (int q = 0; q < 4; q++) {
                    float v = fmaxf(a[i][j][q] + bias[j], 0.f);
                    int row = wr + i * 16 + lq * 4 + q;
                    int col = wc + j * 16 + lrow;
                    int byte = (row * 256 + col * 2) ^ ((row & 7) << 4);
                    *(unsigned short*)&Hl[byte] = f2bf(v);
                }
            }
        }
        __syncthreads();
        // ---- phase B: oacc += Hl @ Wf2[chunk,:] ----
#pragma unroll
        for (int ks = 0; ks < 4; ks++) {
            int k0 = ks * 32;
            bf16x8 hf[2], b2[4];
#pragma unroll
            for (int i = 0; i < 2; i++) {
                int rr = wr + i * 16 + lrow;
                int byte = (rr * 256 + k0 * 2 + lq * 16) ^ ((rr & 7) << 4);
                hf[i] = *(const bf16x8*)&Hl[byte];
            }
#pragma unroll
            for (int j = 0; j < 4; j++) {
                int kt = ch * 4 + ks;              // abs 32-k tile in [0,16)
                int j16 = (wc >> 4) + j;           // out col tile in [0,8)
                b2[j] = *(const bf16x8*)&Wf2pk[(((size_t)kt * 8 + j16) * 64 + l) * 8];
            }
#pragma unroll
            for (int i = 0; i < 2; i++)
#pragma unroll
                for (int j = 0; j < 4; j++)
                    oacc[i][j] = __builtin_amdgcn_mfma_f32_16x16x32_bf16(hf[i], b2[j], oacc[i][j], 0, 0, 0);
        }
        __syncthreads();
    }
#pragma unroll
    for (int i = 0; i < 2; i++) {
#pragma unroll
        for (int j = 0; j < 4; j++) {
#pragma unroll
            for (int q = 0; q < 4; q++) {
                int n = nb0 + wr + i * 16 + lq * 4 + q;
                if (n < NN) out[(size_t)n * DD + wc + j * 16 + lrow] = oacc[i][j][q];
            }
        }
    }
}

extern "C" void kernel_launch(void* const* d_in, const int* in_sizes, int n_in,
                              void* d_out, int out_size, void* d_ws, size_t ws_size,
                              hipStream_t stream) {
    const float* nf  = (const float*)d_in[0];
    const int*   ei  = (const int*)d_in[1];
    const float* ew  = (const float*)d_in[2];
    const float* W1  = (const float*)d_in[3];
    const float* as1 = (const float*)d_in[4];
    const float* ad1 = (const float*)d_in[5];
    const float* We1 = (const float*)d_in[6];
    const float* ae1 = (const float*)d_in[7];
    const float* b1  = (const float*)d_in[8];
    const float* g1  = (const float*)d_in[9];
    const float* be1 = (const float*)d_in[10];
    const float* W2  = (const float*)d_in[11];
    const float* as2 = (const float*)d_in[12];
    const float* ad2 = (const float*)d_in[13];
    const float* We2 = (const float*)d_in[14];
    const float* ae2 = (const float*)d_in[15];
    const float* b2  = (const float*)d_in[16];
    const float* g2  = (const float*)d_in[17];
    const float* be2 = (const float*)d_in[18];
    const float* Wf1 = (const float*)d_in[19];
    const float* bf1 = (const float*)d_in[20];
    const float* Wf2 = (const float*)d_in[21];
    const float* bf2 = (const float*)d_in[22];
    const float* g3  = (const float*)d_in[23];
    const float* be3 = (const float*)d_in[24];
    float* out = (float*)d_out;

    char* p = (char*)d_ws;
    auto alloc = [&](size_t bytes) {
        char* r = p;
        p += (bytes + 255) & ~(size_t)255;
        return r;
    };
    float* nf_cur = (float*)alloc((size_t)NN * DD * 4);
    float* h_out  = (float*)alloc((size_t)NN * DD * 4);
    unsigned short* xh_bf = (unsigned short*)alloc((size_t)NN * DD * 2);
    float* s_e    = (float*)alloc((size_t)NE * HH * 4);
    float* s_src  = (float*)alloc((size_t)NN * HH * 4);
    float* s_dst  = (float*)alloc((size_t)NN * HH * 4);
    int* row_start = (int*)alloc((size_t)(NN + 1) * 4);
    int* cnt       = (int*)alloc((size_t)NN * 4);
    int* cursor    = (int*)alloc((size_t)NN * 4);
    int* partials  = (int*)alloc((size_t)SCAN_NB * 4);
    int* e_src     = (int*)alloc((size_t)NE * 4);
    int* perm      = (int*)alloc((size_t)NE * 4);
    unsigned short* W1pk  = (unsigned short*)alloc((size_t)DD * DD * 2);
    unsigned short* W2pk  = (unsigned short*)alloc((size_t)DD * DD * 2);
    unsigned short* Wf1pk = (unsigned short*)alloc((size_t)DD * DFF * 2);
    unsigned short* Wf2pk = (unsigned short*)alloc((size_t)DFF * DD * 2);

    int ebl = (NE + 255) / 256;
    int nbl = (NN + 255) / 256;

    // weight pack+cvt (tiny, once): fragment-order bf16
    cvtpack_k<<<(DD * DD + 255) / 256, 256, 0, stream>>>(W1, W1pk, DD, DD);
    cvtpack_k<<<(DD * DD + 255) / 256, 256, 0, stream>>>(W2, W2pk, DD, DD);
    cvtpack_k<<<(DD * DFF + 255) / 256, 256, 0, stream>>>(Wf1, Wf1pk, DD, DFF);   // K=128,N=512
    cvtpack_k<<<(DD * DFF + 255) / 256, 256, 0, stream>>>(Wf2, Wf2pk, DFF, DD);   // K=512,N=128

    // CSR build (hierarchical scan)
    zero_int_k<<<nbl, 256, 0, stream>>>(cnt, NN);
    count_k<<<ebl, 256, 0, stream>>>(ei + NE, cnt);
    blksum_k<<<SCAN_NB, 256, 0, stream>>>(cnt, partials);
    scanpart_k<<<1, 256, 0, stream>>>(partials);
    scanapply_k<<<SCAN_NB, 256, 0, stream>>>(cnt, partials, row_start, cursor);
    scatter_k<<<ebl, 256, 0, stream>>>(ei, cursor, e_src, perm);

    int gbl = (NN + 127) / 128;
    int wbl = (NN + 3) / 4;
    int sbl = (NN * HH + 255) / 256;

    // ---- GAT layer 1 ----
    se_k<<<ebl, 256, 0, stream>>>(ew, We1, ae1, perm, s_e);
    gemm_mfma_k<<<gbl, 256, 0, stream>>>(nf, W1pk, xh_bf);
    ssd_k<<<sbl, 256, 0, stream>>>(xh_bf, as1, ad1, s_src, s_dst);
    agg_k<<<wbl, 256, 0, stream>>>(row_start, e_src, s_src, s_dst, s_e, xh_bf, h_out);
    ln_k<<<wbl, 256, 0, stream>>>(h_out, b1, g1, be1, nf, nf_cur);

    // ---- GAT layer 2 ----
    se_k<<<ebl, 256, 0, stream>>>(ew, We2, ae2, perm, s_e);
    gemm_mfma_k<<<gbl, 256, 0, stream>>>(nf_cur, W2pk, xh_bf);
    ssd_k<<<sbl, 256, 0, stream>>>(xh_bf, as2, ad2, s_src, s_dst);
    agg_k<<<wbl, 256, 0, stream>>>(row_start, e_src, s_src, s_dst, s_e, xh_bf, h_out);
    ln_k<<<wbl, 256, 0, stream>>>(h_out, b2, g2, be2, nf_cur, nf_cur);

    // ---- FFN ----
    ffn_mfma_k<<<(NN + 63) / 64, 256, 0, stream>>>(nf_cur, Wf1pk, bf1, Wf2pk, h_out);
    ln_k<<<wbl, 256, 0, stream>>>(h_out, bf2, g3, be3, nf_cur, out);
}

// Round 8
// 320.509 us; speedup vs baseline: 1.2967x; 1.1649x over previous
//
#include <hip/hip_runtime.h>
#include <hip/hip_bf16.h>

#define NN 50000
#define NE 800000
#define DD 128
#define HH 8
#define CC 16
#define DFF 512
#define ED 16
#define SCAN_NB ((NN + 255) / 256)   // 196

typedef __attribute__((ext_vector_type(8))) short bf16x8;
typedef __attribute__((ext_vector_type(4))) float f32x4;

union U8 { bf16x8 v; unsigned short s[8]; };

__device__ inline unsigned short f2bf(float f) {
    union { float f; unsigned u; } v; v.f = f;
    return (unsigned short)((v.u + 0x7fffu + ((v.u >> 16) & 1u)) >> 16);
}
__device__ inline float bf2f(unsigned s) {
    union { unsigned u; float f; } v; v.u = s << 16;
    return v.f;
}

// ---------------- utility ----------------
__global__ void zero_int_k(int* __restrict__ a, int n) {
    int i = blockIdx.x * 256 + threadIdx.x;
    if (i < n) a[i] = 0;
}

// pack weights into MFMA B-fragment order:
// Wpk[((kt*(N/16)+jc)*64 + l)*8 + e] = bf16( W[kt*32+(l>>4)*8+e][jc*16+(l&15)] )
__global__ void cvtpack_k(const float* __restrict__ W, unsigned short* __restrict__ Wpk,
                          int K, int N) {
    int idx = blockIdx.x * 256 + threadIdx.x;
    if (idx >= K * N) return;
    int e = idx & 7;
    int l = (idx >> 3) & 63;
    int r = idx >> 9;
    int n16 = N >> 4;
    int jc = r % n16;
    int kt = r / n16;
    int k = kt * 32 + (l >> 4) * 8 + e;
    int n = jc * 16 + (l & 15);
    Wpk[idx] = f2bf(W[(size_t)k * N + n]);
}

// ---------------- CSR build ----------------
__global__ void count_k(const int* __restrict__ dst, int* __restrict__ cnt) {
    int e = blockIdx.x * 256 + threadIdx.x;
    if (e < NE) atomicAdd(&cnt[dst[e]], 1);
}

__global__ void blksum_k(const int* __restrict__ cnt, int* __restrict__ partials) {
    int i = blockIdx.x * 256 + threadIdx.x;
    int v = (i < NN) ? cnt[i] : 0;
#pragma unroll
    for (int m = 1; m < 64; m <<= 1) v += __shfl_xor(v, m, 64);
    __shared__ int ws[4];
    if ((threadIdx.x & 63) == 0) ws[threadIdx.x >> 6] = v;
    __syncthreads();
    if (threadIdx.x == 0) partials[blockIdx.x] = ws[0] + ws[1] + ws[2] + ws[3];
}

__global__ void scanpart_k(int* __restrict__ partials) {
    __shared__ int buf[256];
    int t = threadIdx.x;
    int v = (t < SCAN_NB) ? partials[t] : 0;
    buf[t] = v;
    __syncthreads();
    for (int off = 1; off < 256; off <<= 1) {
        int u = (t >= off) ? buf[t - off] : 0;
        __syncthreads();
        buf[t] += u;
        __syncthreads();
    }
    if (t < SCAN_NB) partials[t] = buf[t] - v;  // exclusive
}

__global__ void scanapply_k(const int* __restrict__ cnt, const int* __restrict__ partials,
                            int* __restrict__ row_start, int* __restrict__ cursor) {
    __shared__ int buf[256];
    int t = threadIdx.x;
    int i = blockIdx.x * 256 + t;
    int v = (i < NN) ? cnt[i] : 0;
    buf[t] = v;
    __syncthreads();
    for (int off = 1; off < 256; off <<= 1) {
        int u = (t >= off) ? buf[t - off] : 0;
        __syncthreads();
        buf[t] += u;
        __syncthreads();
    }
    int excl = buf[t] - v + partials[blockIdx.x];
    if (i < NN) {
        row_start[i] = excl;
        cursor[i] = excl;
        if (i == NN - 1) row_start[NN] = excl + v;
    }
}

__global__ void scatter_k(const int* __restrict__ ei, int* __restrict__ cursor,
                          int2* __restrict__ es_eid) {
    int e = blockIdx.x * 256 + threadIdx.x;
    if (e >= NE) return;
    int s = ei[e];
    int d = ei[NE + e];
    int pos = atomicAdd(&cursor[d], 1);
    es_eid[pos] = make_int2(s, e);
}

// ---------------- edge scores, both layers, CSR order ----------------
// s_eL[p,h] = ew[eid[p]] . AeL[:,h]
__global__ void se2_k(const float* __restrict__ ew, const int2* __restrict__ es_eid,
                      const float* __restrict__ We1, const float* __restrict__ ae1,
                      const float* __restrict__ We2, const float* __restrict__ ae2,
                      float* __restrict__ s_e1, float* __restrict__ s_e2) {
    __shared__ float A1[ED * HH], A2[ED * HH];
    int t = threadIdx.x;
    if (t < 128) {
        int k = t >> 3, h = t & 7;
        float s = 0.f;
#pragma unroll
        for (int c = 0; c < CC; c++) s += We1[k * DD + h * CC + c] * ae1[h * CC + c];
        A1[t] = s;
    } else {
        int u = t - 128;
        int k = u >> 3, h = u & 7;
        float s = 0.f;
#pragma unroll
        for (int c = 0; c < CC; c++) s += We2[k * DD + h * CC + c] * ae2[h * CC + c];
        A2[u] = s;
    }
    __syncthreads();
    int p = blockIdx.x * 256 + t;
    if (p >= NE) return;
    int eid = es_eid[p].y;
    const float* ep = &ew[(size_t)eid * ED];
    float4 v0 = *(const float4*)(ep);
    float4 v1 = *(const float4*)(ep + 4);
    float4 v2 = *(const float4*)(ep + 8);
    float4 v3 = *(const float4*)(ep + 12);
    float ev[16] = {v0.x, v0.y, v0.z, v0.w, v1.x, v1.y, v1.z, v1.w,
                    v2.x, v2.y, v2.z, v2.w, v3.x, v3.y, v3.z, v3.w};
    float o1[8] = {0, 0, 0, 0, 0, 0, 0, 0};
    float o2[8] = {0, 0, 0, 0, 0, 0, 0, 0};
#pragma unroll
    for (int k = 0; k < 16; k++) {
        float v = ev[k];
#pragma unroll
        for (int h = 0; h < 8; h++) {
            o1[h] += v * A1[k * 8 + h];
            o2[h] += v * A2[k * 8 + h];
        }
    }
    *(float4*)&s_e1[(size_t)p * 8]     = make_float4(o1[0], o1[1], o1[2], o1[3]);
    *(float4*)&s_e1[(size_t)p * 8 + 4] = make_float4(o1[4], o1[5], o1[6], o1[7]);
    *(float4*)&s_e2[(size_t)p * 8]     = make_float4(o2[0], o2[1], o2[2], o2[3]);
    *(float4*)&s_e2[(size_t)p * 8 + 4] = make_float4(o2[4], o2[5], o2[6], o2[7]);
}

// ---------------- MFMA node GEMM: Ybf = bf16(X @ W), W packed in fragment order ----------------
__global__ __launch_bounds__(256) void gemm_mfma_k(const float* __restrict__ X,
                                                   const unsigned short* __restrict__ Wpk,
                                                   unsigned short* __restrict__ Ybf) {
    __shared__ char Xl[128 * 256];  // bf16 [row][128], XOR-swizzled
    int t = threadIdx.x;
    int nb0 = blockIdx.x * 128;
    for (int c = t; c < 2048; c += 256) {
        int row = c >> 4, cb = c & 15;
        int n = nb0 + row;
        U8 u;
        if (n < NN) {
            const float* xp = &X[(size_t)n * DD + cb * 8];
            float4 a = *(const float4*)xp;
            float4 b = *(const float4*)(xp + 4);
            u.s[0] = f2bf(a.x); u.s[1] = f2bf(a.y); u.s[2] = f2bf(a.z); u.s[3] = f2bf(a.w);
            u.s[4] = f2bf(b.x); u.s[5] = f2bf(b.y); u.s[6] = f2bf(b.z); u.s[7] = f2bf(b.w);
        } else {
#pragma unroll
            for (int q = 0; q < 8; q++) u.s[q] = 0;
        }
        int byte = (row * 256 + cb * 16) ^ ((row & 7) << 4);
        *(bf16x8*)&Xl[byte] = u.v;
    }
    __syncthreads();
    int w = t >> 6, l = t & 63;
    int lrow = l & 15, lq = l >> 4;
    int r0 = (w & 1) * 64, c0 = (w >> 1) * 64;
    f32x4 acc[4][4];
#pragma unroll
    for (int i = 0; i < 4; i++)
#pragma unroll
        for (int j = 0; j < 4; j++) acc[i][j] = (f32x4){0.f, 0.f, 0.f, 0.f};
#pragma unroll
    for (int ks = 0; ks < 4; ks++) {
        int k0 = ks * 32;
        bf16x8 af[4], bq[4];
#pragma unroll
        for (int i = 0; i < 4; i++) {
            int rr = r0 + i * 16 + lrow;
            int byte = (rr * 256 + k0 * 2 + lq * 16) ^ ((rr & 7) << 4);
            af[i] = *(const bf16x8*)&Xl[byte];
        }
#pragma unroll
        for (int j = 0; j < 4; j++) {
            int j16 = (c0 >> 4) + j;
            bq[j] = *(const bf16x8*)&Wpk[(((size_t)ks * 8 + j16) * 64 + l) * 8];
        }
#pragma unroll
        for (int i = 0; i < 4; i++)
#pragma unroll
            for (int j = 0; j < 4; j++)
                acc[i][j] = __builtin_amdgcn_mfma_f32_16x16x32_bf16(af[i], bq[j], acc[i][j], 0, 0, 0);
    }
#pragma unroll
    for (int i = 0; i < 4; i++) {
#pragma unroll
        for (int j = 0; j < 4; j++) {
#pragma unroll
            for (int q = 0; q < 4; q++) {
                int n = nb0 + r0 + i * 16 + lq * 4 + q;
                if (n < NN) Ybf[(size_t)n * DD + c0 + j * 16 + lrow] = f2bf(acc[i][j][q]);
            }
        }
    }
}

// ---------------- s_src/s_dst from bf16 xh ----------------
__global__ void ssd_k(const unsigned short* __restrict__ xh_bf, const float* __restrict__ a_src,
                      const float* __restrict__ a_dst, float* __restrict__ s_src,
                      float* __restrict__ s_dst) {
    __shared__ float as[128], ad[128];
    if (threadIdx.x < 128) {
        as[threadIdx.x] = a_src[threadIdx.x];
        ad[threadIdx.x] = a_dst[threadIdx.x];
    }
    __syncthreads();
    int idx = blockIdx.x * 256 + threadIdx.x;
    if (idx >= NN * HH) return;
    int n = idx >> 3, h = idx & 7;
    const unsigned short* x = &xh_bf[(size_t)n * DD + h * CC];
    U8 u0, u1;
    u0.v = *(const bf16x8*)(x);
    u1.v = *(const bf16x8*)(x + 8);
    float s1 = 0.f, s2 = 0.f;
#pragma unroll
    for (int c = 0; c < 8; c++) {
        float v = bf2f(u0.s[c]);
        s1 += v * as[h * CC + c];
        s2 += v * ad[h * CC + c];
    }
#pragma unroll
    for (int c = 0; c < 8; c++) {
        float v = bf2f(u1.s[c]);
        s1 += v * as[h * CC + 8 + c];
        s2 += v * ad[h * CC + 8 + c];
    }
    s_src[idx] = s1;
    s_dst[idx] = s2;
}

// ---------------- fused aggregation + bias + LayerNorm + leaky + residual ----------------
__global__ __launch_bounds__(256) void agg_ln_k(const int* __restrict__ row_start,
                                                const int2* __restrict__ es_eid,
                                                const float* __restrict__ s_src,
                                                const float* __restrict__ s_dst,
                                                const float* __restrict__ s_e,
                                                const unsigned short* __restrict__ xh_bf,
                                                const float* __restrict__ bias,
                                                const float* __restrict__ g,
                                                const float* __restrict__ be,
                                                const float* __restrict__ res,
                                                float* __restrict__ outNf) {
    int wid = (blockIdx.x * 256 + threadIdx.x) >> 6;
    if (wid >= NN) return;
    int lane = threadIdx.x & 63;
    int h = lane >> 3;
    float sdst = s_dst[wid * 8 + h];
    int beg = row_start[wid], end = row_start[wid + 1];
    float acc0 = 0.f, acc1 = 0.f, z = 0.f;
    int p = beg;
    for (; p + 4 <= end; p += 4) {
        int q0 = es_eid[p].x;
        int q1 = es_eid[p + 1].x;
        int q2 = es_eid[p + 2].x;
        int q3 = es_eid[p + 3].x;
        float a0 = s_src[q0 * 8 + h] + sdst + s_e[(size_t)p * 8 + h];
        float a1 = s_src[q1 * 8 + h] + sdst + s_e[(size_t)(p + 1) * 8 + h];
        float a2 = s_src[q2 * 8 + h] + sdst + s_e[(size_t)(p + 2) * 8 + h];
        float a3 = s_src[q3 * 8 + h] + sdst + s_e[(size_t)(p + 3) * 8 + h];
        unsigned u0 = *(const unsigned*)&xh_bf[(size_t)q0 * DD + lane * 2];
        unsigned u1 = *(const unsigned*)&xh_bf[(size_t)q1 * DD + lane * 2];
        unsigned u2 = *(const unsigned*)&xh_bf[(size_t)q2 * DD + lane * 2];
        unsigned u3 = *(const unsigned*)&xh_bf[(size_t)q3 * DD + lane * 2];
        a0 = (a0 > 0.f) ? a0 : 0.2f * a0;
        a1 = (a1 > 0.f) ? a1 : 0.2f * a1;
        a2 = (a2 > 0.f) ? a2 : 0.2f * a2;
        a3 = (a3 > 0.f) ? a3 : 0.2f * a3;
        float e0 = __expf(a0);
        float e1 = __expf(a1);
        float e2 = __expf(a2);
        float e3 = __expf(a3);
        z += (e0 + e1) + (e2 + e3);
        acc0 = fmaf(e0, bf2f(u0 & 0xffffu), acc0);
        acc1 = fmaf(e0, bf2f(u0 >> 16), acc1);
        acc0 = fmaf(e1, bf2f(u1 & 0xffffu), acc0);
        acc1 = fmaf(e1, bf2f(u1 >> 16), acc1);
        acc0 = fmaf(e2, bf2f(u2 & 0xffffu), acc0);
        acc1 = fmaf(e2, bf2f(u2 >> 16), acc1);
        acc0 = fmaf(e3, bf2f(u3 & 0xffffu), acc0);
        acc1 = fmaf(e3, bf2f(u3 >> 16), acc1);
    }
    for (; p < end; p++) {
        int q0 = es_eid[p].x;
        float a0 = s_src[q0 * 8 + h] + sdst + s_e[(size_t)p * 8 + h];
        unsigned u0 = *(const unsigned*)&xh_bf[(size_t)q0 * DD + lane * 2];
        a0 = (a0 > 0.f) ? a0 : 0.2f * a0;
        float e0 = __expf(a0);
        z += e0;
        acc0 = fmaf(e0, bf2f(u0 & 0xffffu), acc0);
        acc1 = fmaf(e0, bf2f(u0 >> 16), acc1);
    }
    float inv = 1.f / (z + 1e-16f);
    float2 b = *(const float2*)&bias[lane * 2];
    float x0 = acc0 * inv + b.x;
    float x1 = acc1 * inv + b.y;
    // LayerNorm (ddof=1) + leaky(0.01) + residual
    float s = x0 + x1;
    float q = x0 * x0 + x1 * x1;
#pragma unroll
    for (int m = 1; m < 64; m <<= 1) {
        s += __shfl_xor(s, m, 64);
        q += __shfl_xor(q, m, 64);
    }
    float mu = s * (1.f / 128.f);
    float var = (q - 128.f * mu * mu) * (1.f / 127.f);
    float sd = sqrtf(fmaxf(var, 0.f));
    float invs = 1.f / (sd + 1e-6f);
    float2 gg = *(const float2*)&g[lane * 2];
    float2 bb = *(const float2*)&be[lane * 2];
    float y0 = gg.x * (x0 - mu) * invs + bb.x;
    float y1 = gg.y * (x1 - mu) * invs + bb.y;
    y0 = (y0 > 0.f) ? y0 : 0.01f * y0;
    y1 = (y1 > 0.f) ? y1 : 0.01f * y1;
    float2 r = *(const float2*)&res[(size_t)wid * DD + lane * 2];
    *(float2*)&outNf[(size_t)wid * DD + lane * 2] = make_float2(r.x + y0, r.y + y1);
}

// ---------------- bias + LayerNorm(ddof=1) + leaky_relu + residual ----------------
__global__ __launch_bounds__(256) void ln_k(const float* __restrict__ hin,
                                            const float* __restrict__ bias,
                                            const float* __restrict__ g,
                                            const float* __restrict__ be,
                                            const float* __restrict__ res,
                                            float* __restrict__ out) {
    int wid = (blockIdx.x * 256 + threadIdx.x) >> 6;
    if (wid >= NN) return;
    int lane = threadIdx.x & 63;
    float2 x = *(const float2*)&hin[(size_t)wid * DD + lane * 2];
    float2 b = *(const float2*)&bias[lane * 2];
    x.x += b.x;
    x.y += b.y;
    float s = x.x + x.y;
    float q = x.x * x.x + x.y * x.y;
#pragma unroll
    for (int m = 1; m < 64; m <<= 1) {
        s += __shfl_xor(s, m, 64);
        q += __shfl_xor(q, m, 64);
    }
    float mu = s * (1.f / 128.f);
    float var = (q - 128.f * mu * mu) * (1.f / 127.f);
    float sd = sqrtf(fmaxf(var, 0.f));
    float inv = 1.f / (sd + 1e-6f);
    float2 gg = *(const float2*)&g[lane * 2];
    float2 bb = *(const float2*)&be[lane * 2];
    float y0 = gg.x * (x.x - mu) * inv + bb.x;
    float y1 = gg.y * (x.y - mu) * inv + bb.y;
    y0 = (y0 > 0.f) ? y0 : 0.01f * y0;
    y1 = (y1 > 0.f) ? y1 : 0.01f * y1;
    float2 r = *(const float2*)&res[(size_t)wid * DD + lane * 2];
    *(float2*)&out[(size_t)wid * DD + lane * 2] = make_float2(r.x + y0, r.y + y1);
}

// ---------------- fused MFMA FFN: 64 nodes/block, hidden in 4 chunks of 128 ----------------
__global__ __launch_bounds__(256) void ffn_mfma_k(const float* __restrict__ X,
                                                  const unsigned short* __restrict__ Wf1pk,
                                                  const float* __restrict__ bf1,
                                                  const unsigned short* __restrict__ Wf2pk,
                                                  float* __restrict__ out) {
    __shared__ char Xl[64 * 256];   // bf16 [64][128] swizzled, 16KB
    __shared__ char Hl[64 * 256];   // bf16 [64][128] swizzled, 16KB
    int t = threadIdx.x;
    int nb0 = blockIdx.x * 64;
    for (int c = t; c < 1024; c += 256) {
        int row = c >> 4, cb = c & 15;
        int n = nb0 + row;
        U8 u;
        if (n < NN) {
            const float* xp = &X[(size_t)n * DD + cb * 8];
            float4 a = *(const float4*)xp;
            float4 b = *(const float4*)(xp + 4);
            u.s[0] = f2bf(a.x); u.s[1] = f2bf(a.y); u.s[2] = f2bf(a.z); u.s[3] = f2bf(a.w);
            u.s[4] = f2bf(b.x); u.s[5] = f2bf(b.y); u.s[6] = f2bf(b.z); u.s[7] = f2bf(b.w);
        } else {
#pragma unroll
            for (int q = 0; q < 8; q++) u.s[q] = 0;
        }
        int byte = (row * 256 + cb * 16) ^ ((row & 7) << 4);
        *(bf16x8*)&Xl[byte] = u.v;
    }
    __syncthreads();
    int w = t >> 6, l = t & 63;
    int lrow = l & 15, lq = l >> 4;
    int wr = (w & 1) * 32;   // wave's node-row base (32 rows)
    int wc = (w >> 1) * 64;  // wave's col base (64 cols of 128)
    f32x4 oacc[2][4];
#pragma unroll
    for (int i = 0; i < 2; i++)
#pragma unroll
        for (int j = 0; j < 4; j++) oacc[i][j] = (f32x4){0.f, 0.f, 0.f, 0.f};

#pragma unroll
    for (int ch = 0; ch < 4; ch++) {
        int hc0 = ch * 128;
        // ---- phase A: S-chunk = relu(X @ Wf1[:,chunk] + b) ----
        f32x4 a[2][4];
#pragma unroll
        for (int i = 0; i < 2; i++)
#pragma unroll
            for (int j = 0; j < 4; j++) a[i][j] = (f32x4){0.f, 0.f, 0.f, 0.f};
#pragma unroll
        for (int ks = 0; ks < 4; ks++) {
            int k0 = ks * 32;
            bf16x8 af[2], bq[4];
#pragma unroll
            for (int i = 0; i < 2; i++) {
                int rr = wr + i * 16 + lrow;
                int byte = (rr * 256 + k0 * 2 + lq * 16) ^ ((rr & 7) << 4);
                af[i] = *(const bf16x8*)&Xl[byte];
            }
#pragma unroll
            for (int j = 0; j < 4; j++) {
                int j16 = ch * 8 + (wc >> 4) + j;   // abs 16-col tile in [0,32)
                bq[j] = *(const bf16x8*)&Wf1pk[(((size_t)ks * 32 + j16) * 64 + l) * 8];
            }
#pragma unroll
            for (int i = 0; i < 2; i++)
#pragma unroll
                for (int j = 0; j < 4; j++)
                    a[i][j] = __builtin_amdgcn_mfma_f32_16x16x32_bf16(af[i], bq[j], a[i][j], 0, 0, 0);
        }
        float bias[4];
#pragma unroll
        for (int j = 0; j < 4; j++) bias[j] = bf1[hc0 + wc + j * 16 + lrow];
#pragma unroll
        for (int i = 0; i < 2; i++) {
#pragma unroll
            for (int j = 0; j < 4; j++) {
#pragma unroll
                for (int q = 0; q < 4; q++) {
                    float v = fmaxf(a[i][j][q] + bias[j], 0.f);
                    int row = wr + i * 16 + lq * 4 + q;
                    int col = wc + j * 16 + lrow;
                    int byte = (row * 256 + col * 2) ^ ((row & 7) << 4);
                    *(unsigned short*)&Hl[byte] = f2bf(v);
                }
            }
        }
        __syncthreads();
        // ---- phase B: oacc += Hl @ Wf2[chunk,:] ----
#pragma unroll
        for (int ks = 0; ks < 4; ks++) {
            int k0 = ks * 32;
            bf16x8 hf[2], b2[4];
#pragma unroll
            for (int i = 0; i < 2; i++) {
                int rr = wr + i * 16 + lrow;
                int byte = (rr * 256 + k0 * 2 + lq * 16) ^ ((rr & 7) << 4);
                hf[i] = *(const bf16x8*)&Hl[byte];
            }
#pragma unroll
            for (int j = 0; j < 4; j++) {
                int kt = ch * 4 + ks;              // abs 32-k tile in [0,16)
                int j16 = (wc >> 4) + j;           // out col tile in [0,8)
                b2[j] = *(const bf16x8*)&Wf2pk[(((size_t)kt * 8 + j16) * 64 + l) * 8];
            }
#pragma unroll
            for (int i = 0; i < 2; i++)
#pragma unroll
                for (int j = 0; j < 4; j++)
                    oacc[i][j] = __builtin_amdgcn_mfma_f32_16x16x32_bf16(hf[i], b2[j], oacc[i][j], 0, 0, 0);
        }
        __syncthreads();
    }
#pragma unroll
    for (int i = 0; i < 2; i++) {
#pragma unroll
        for (int j = 0; j < 4; j++) {
#pragma unroll
            for (int q = 0; q < 4; q++) {
                int n = nb0 + wr + i * 16 + lq * 4 + q;
                if (n < NN) out[(size_t)n * DD + wc + j * 16 + lrow] = oacc[i][j][q];
            }
        }
    }
}

extern "C" void kernel_launch(void* const* d_in, const int* in_sizes, int n_in,
                              void* d_out, int out_size, void* d_ws, size_t ws_size,
                              hipStream_t stream) {
    const float* nf  = (const float*)d_in[0];
    const int*   ei  = (const int*)d_in[1];
    const float* ew  = (const float*)d_in[2];
    const float* W1  = (const float*)d_in[3];
    const float* as1 = (const float*)d_in[4];
    const float* ad1 = (const float*)d_in[5];
    const float* We1 = (const float*)d_in[6];
    const float* ae1 = (const float*)d_in[7];
    const float* b1  = (const float*)d_in[8];
    const float* g1  = (const float*)d_in[9];
    const float* be1 = (const float*)d_in[10];
    const float* W2  = (const float*)d_in[11];
    const float* as2 = (const float*)d_in[12];
    const float* ad2 = (const float*)d_in[13];
    const float* We2 = (const float*)d_in[14];
    const float* ae2 = (const float*)d_in[15];
    const float* b2  = (const float*)d_in[16];
    const float* g2  = (const float*)d_in[17];
    const float* be2 = (const float*)d_in[18];
    const float* Wf1 = (const float*)d_in[19];
    const float* bf1 = (const float*)d_in[20];
    const float* Wf2 = (const float*)d_in[21];
    const float* bf2 = (const float*)d_in[22];
    const float* g3  = (const float*)d_in[23];
    const float* be3 = (const float*)d_in[24];
    float* out = (float*)d_out;

    char* p = (char*)d_ws;
    auto alloc = [&](size_t bytes) {
        char* r = p;
        p += (bytes + 255) & ~(size_t)255;
        return r;
    };
    float* nf_cur = (float*)alloc((size_t)NN * DD * 4);
    float* h_out  = (float*)alloc((size_t)NN * DD * 4);
    unsigned short* xh_bf = (unsigned short*)alloc((size_t)NN * DD * 2);
    float* s_e1   = (float*)alloc((size_t)NE * HH * 4);
    float* s_e2   = (float*)alloc((size_t)NE * HH * 4);
    float* s_src  = (float*)alloc((size_t)NN * HH * 4);
    float* s_dst  = (float*)alloc((size_t)NN * HH * 4);
    int* row_start = (int*)alloc((size_t)(NN + 1) * 4);
    int* cnt       = (int*)alloc((size_t)NN * 4);
    int* cursor    = (int*)alloc((size_t)NN * 4);
    int* partials  = (int*)alloc((size_t)SCAN_NB * 4);
    int2* es_eid   = (int2*)alloc((size_t)NE * 8);
    unsigned short* W1pk  = (unsigned short*)alloc((size_t)DD * DD * 2);
    unsigned short* W2pk  = (unsigned short*)alloc((size_t)DD * DD * 2);
    unsigned short* Wf1pk = (unsigned short*)alloc((size_t)DD * DFF * 2);
    unsigned short* Wf2pk = (unsigned short*)alloc((size_t)DFF * DD * 2);

    int ebl = (NE + 255) / 256;
    int nbl = (NN + 255) / 256;

    // weight pack+cvt (tiny, once): fragment-order bf16
    cvtpack_k<<<(DD * DD + 255) / 256, 256, 0, stream>>>(W1, W1pk, DD, DD);
    cvtpack_k<<<(DD * DD + 255) / 256, 256, 0, stream>>>(W2, W2pk, DD, DD);
    cvtpack_k<<<(DD * DFF + 255) / 256, 256, 0, stream>>>(Wf1, Wf1pk, DD, DFF);   // K=128,N=512
    cvtpack_k<<<(DD * DFF + 255) / 256, 256, 0, stream>>>(Wf2, Wf2pk, DFF, DD);   // K=512,N=128

    // CSR build (hierarchical scan)
    zero_int_k<<<nbl, 256, 0, stream>>>(cnt, NN);
    count_k<<<ebl, 256, 0, stream>>>(ei + NE, cnt);
    blksum_k<<<SCAN_NB, 256, 0, stream>>>(cnt, partials);
    scanpart_k<<<1, 256, 0, stream>>>(partials);
    scanapply_k<<<SCAN_NB, 256, 0, stream>>>(cnt, partials, row_start, cursor);
    scatter_k<<<ebl, 256, 0, stream>>>(ei, cursor, es_eid);

    // edge scores for BOTH layers, coalesced writes
    se2_k<<<ebl, 256, 0, stream>>>(ew, es_eid, We1, ae1, We2, ae2, s_e1, s_e2);

    int gbl = (NN + 127) / 128;
    int wbl = (NN + 3) / 4;
    int sbl = (NN * HH + 255) / 256;

    // ---- GAT layer 1 ----
    gemm_mfma_k<<<gbl, 256, 0, stream>>>(nf, W1pk, xh_bf);
    ssd_k<<<sbl, 256, 0, stream>>>(xh_bf, as1, ad1, s_src, s_dst);
    agg_ln_k<<<wbl, 256, 0, stream>>>(row_start, es_eid, s_src, s_dst, s_e1, xh_bf,
                                      b1, g1, be1, nf, nf_cur);

    // ---- GAT layer 2 ----
    gemm_mfma_k<<<gbl, 256, 0, stream>>>(nf_cur, W2pk, xh_bf);
    ssd_k<<<sbl, 256, 0, stream>>>(xh_bf, as2, ad2, s_src, s_dst);
    agg_ln_k<<<wbl, 256, 0, stream>>>(row_start, es_eid, s_src, s_dst, s_e2, xh_bf,
                                      b2, g2, be2, nf_cur, nf_cur);

    // ---- FFN ----
    ffn_mfma_k<<<(NN + 63) / 64, 256, 0, stream>>>(nf_cur, Wf1pk, bf1, Wf2pk, h_out);
    ln_k<<<wbl, 256, 0, stream>>>(h_out, bf2, g3, be3, nf_cur, out);
}

// Round 9
// 303.309 us; speedup vs baseline: 1.3702x; 1.0567x over previous
//
#include <hip/hip_runtime.h>
#include <hip/hip_bf16.h>

#define NN 50000
#define NE 800000
#define DD 128
#define HH 8
#define CC 16
#define DFF 512
#define ED 16
#define SCAN_NB ((NN + 255) / 256)   // 196
#define BKT 256
#define NBKT ((NN + BKT - 1) / BKT)  // 196
#define EPB 4096

typedef __attribute__((ext_vector_type(8))) short bf16x8;
typedef __attribute__((ext_vector_type(4))) float f32x4;

union U8 { bf16x8 v; unsigned short s[8]; };

__device__ inline unsigned short f2bf(float f) {
    union { float f; unsigned u; } v; v.f = f;
    return (unsigned short)((v.u + 0x7fffu + ((v.u >> 16) & 1u)) >> 16);
}
__device__ inline float bf2f(unsigned s) {
    union { unsigned u; float f; } v; v.u = s << 16;
    return v.f;
}

// ---------------- utility ----------------
__global__ void zero_int_k(int* __restrict__ a, int n) {
    int i = blockIdx.x * 256 + threadIdx.x;
    if (i < n) a[i] = 0;
}

// pack weights into MFMA B-fragment order
__global__ void cvtpack_k(const float* __restrict__ W, unsigned short* __restrict__ Wpk,
                          int K, int N) {
    int idx = blockIdx.x * 256 + threadIdx.x;
    if (idx >= K * N) return;
    int e = idx & 7;
    int l = (idx >> 3) & 63;
    int r = idx >> 9;
    int n16 = N >> 4;
    int jc = r % n16;
    int kt = r / n16;
    int k = kt * 32 + (l >> 4) * 8 + e;
    int n = jc * 16 + (l & 15);
    Wpk[idx] = f2bf(W[(size_t)k * N + n]);
}

// ---------------- CSR build ----------------
__global__ void count_k(const int* __restrict__ dst, int* __restrict__ cnt) {
    int e = blockIdx.x * 256 + threadIdx.x;
    if (e < NE) atomicAdd(&cnt[dst[e]], 1);
}

__global__ void blksum_k(const int* __restrict__ cnt, int* __restrict__ partials) {
    int i = blockIdx.x * 256 + threadIdx.x;
    int v = (i < NN) ? cnt[i] : 0;
#pragma unroll
    for (int m = 1; m < 64; m <<= 1) v += __shfl_xor(v, m, 64);
    __shared__ int ws[4];
    if ((threadIdx.x & 63) == 0) ws[threadIdx.x >> 6] = v;
    __syncthreads();
    if (threadIdx.x == 0) partials[blockIdx.x] = ws[0] + ws[1] + ws[2] + ws[3];
}

__global__ void scanpart_k(int* __restrict__ partials) {
    __shared__ int buf[256];
    int t = threadIdx.x;
    int v = (t < SCAN_NB) ? partials[t] : 0;
    buf[t] = v;
    __syncthreads();
    for (int off = 1; off < 256; off <<= 1) {
        int u = (t >= off) ? buf[t - off] : 0;
        __syncthreads();
        buf[t] += u;
        __syncthreads();
    }
    if (t < SCAN_NB) partials[t] = buf[t] - v;  // exclusive
}

__global__ void scanapply_k(const int* __restrict__ cnt, const int* __restrict__ partials,
                            int* __restrict__ row_start, int* __restrict__ cursor) {
    __shared__ int buf[256];
    int t = threadIdx.x;
    int i = blockIdx.x * 256 + t;
    int v = (i < NN) ? cnt[i] : 0;
    buf[t] = v;
    __syncthreads();
    for (int off = 1; off < 256; off <<= 1) {
        int u = (t >= off) ? buf[t - off] : 0;
        __syncthreads();
        buf[t] += u;
        __syncthreads();
    }
    int excl = buf[t] - v + partials[blockIdx.x];
    if (i < NN) {
        row_start[i] = excl;
        cursor[i] = excl;
        if (i == NN - 1) row_start[NN] = excl + v;
    }
}

__global__ void bucketbase_k(const int* __restrict__ row_start, int* __restrict__ bucket_cursor) {
    int b = blockIdx.x * 256 + threadIdx.x;
    if (b < NBKT) bucket_cursor[b] = row_start[b * BKT];
}

// pass A: bin edges into bucket-major order with LDS-chunked (burst) writes
__global__ __launch_bounds__(256) void bin_k(const int* __restrict__ ei,
                                             int* __restrict__ bucket_cursor,
                                             int2* __restrict__ binned) {
    __shared__ int hist[NBKT];
    __shared__ int base[NBKT];
    int t = threadIdx.x;
    int e0 = blockIdx.x * EPB;
    int eend = e0 + EPB; if (eend > NE) eend = NE;
    if (t < NBKT) hist[t] = 0;
    __syncthreads();
    for (int e = e0 + t; e < eend; e += 256) {
        int d = ei[NE + e];
        atomicAdd(&hist[d >> 8], 1);
    }
    __syncthreads();
    if (t < NBKT) {
        int c = hist[t];
        base[t] = c ? atomicAdd(&bucket_cursor[t], c) : 0;
        hist[t] = 0;   // reuse as local cursor
    }
    __syncthreads();
    for (int e = e0 + t; e < eend; e += 256) {
        int s = ei[e];
        int d = ei[NE + e];
        int b = d >> 8;
        int loc = atomicAdd(&hist[b], 1);
        binned[base[b] + loc] = make_int2(s | ((d & 255) << 16), e);
    }
}

// pass B: per-bucket CSR scatter (writes confined to one ~32KB L2-local region)
__global__ __launch_bounds__(256) void csr_scatter_k(const int2* __restrict__ binned,
                                                     const int* __restrict__ row_start,
                                                     int* __restrict__ cursor,
                                                     int2* __restrict__ es_eid) {
    int b = blockIdx.x;
    int beg = row_start[b * BKT];
    int endNode = (b + 1) * BKT; if (endNode > NN) endNode = NN;
    int end = row_start[endNode];
    for (int p = beg + threadIdx.x; p < end; p += 256) {
        int2 r = binned[p];
        int d = b * BKT + (r.x >> 16);
        int pos = atomicAdd(&cursor[d], 1);
        es_eid[pos] = make_int2(r.x & 0xffff, r.y);
    }
}

// ---------------- edge scores, both layers, CSR order ----------------
__global__ void se2_k(const float* __restrict__ ew, const int2* __restrict__ es_eid,
                      const float* __restrict__ We1, const float* __restrict__ ae1,
                      const float* __restrict__ We2, const float* __restrict__ ae2,
                      float* __restrict__ s_e1, float* __restrict__ s_e2) {
    __shared__ float A1[ED * HH], A2[ED * HH];
    int t = threadIdx.x;
    if (t < 128) {
        int k = t >> 3, h = t & 7;
        float s = 0.f;
#pragma unroll
        for (int c = 0; c < CC; c++) s += We1[k * DD + h * CC + c] * ae1[h * CC + c];
        A1[t] = s;
    } else {
        int u = t - 128;
        int k = u >> 3, h = u & 7;
        float s = 0.f;
#pragma unroll
        for (int c = 0; c < CC; c++) s += We2[k * DD + h * CC + c] * ae2[h * CC + c];
        A2[u] = s;
    }
    __syncthreads();
    int p = blockIdx.x * 256 + t;
    if (p >= NE) return;
    int eid = es_eid[p].y;
    const float* ep = &ew[(size_t)eid * ED];
    float4 v0 = *(const float4*)(ep);
    float4 v1 = *(const float4*)(ep + 4);
    float4 v2 = *(const float4*)(ep + 8);
    float4 v3 = *(const float4*)(ep + 12);
    float ev[16] = {v0.x, v0.y, v0.z, v0.w, v1.x, v1.y, v1.z, v1.w,
                    v2.x, v2.y, v2.z, v2.w, v3.x, v3.y, v3.z, v3.w};
    float o1[8] = {0, 0, 0, 0, 0, 0, 0, 0};
    float o2[8] = {0, 0, 0, 0, 0, 0, 0, 0};
#pragma unroll
    for (int k = 0; k < 16; k++) {
        float v = ev[k];
#pragma unroll
        for (int h = 0; h < 8; h++) {
            o1[h] += v * A1[k * 8 + h];
            o2[h] += v * A2[k * 8 + h];
        }
    }
    *(float4*)&s_e1[(size_t)p * 8]     = make_float4(o1[0], o1[1], o1[2], o1[3]);
    *(float4*)&s_e1[(size_t)p * 8 + 4] = make_float4(o1[4], o1[5], o1[6], o1[7]);
    *(float4*)&s_e2[(size_t)p * 8]     = make_float4(o2[0], o2[1], o2[2], o2[3]);
    *(float4*)&s_e2[(size_t)p * 8 + 4] = make_float4(o2[4], o2[5], o2[6], o2[7]);
}

// ---------------- MFMA node GEMM: Ybf = bf16(X @ W), W packed in fragment order ----------------
__global__ __launch_bounds__(256) void gemm_mfma_k(const float* __restrict__ X,
                                                   const unsigned short* __restrict__ Wpk,
                                                   unsigned short* __restrict__ Ybf) {
    __shared__ char Xl[128 * 256];  // bf16 [row][128], XOR-swizzled
    int t = threadIdx.x;
    int nb0 = blockIdx.x * 128;
    for (int c = t; c < 2048; c += 256) {
        int row = c >> 4, cb = c & 15;
        int n = nb0 + row;
        U8 u;
        if (n < NN) {
            const float* xp = &X[(size_t)n * DD + cb * 8];
            float4 a = *(const float4*)xp;
            float4 b = *(const float4*)(xp + 4);
            u.s[0] = f2bf(a.x); u.s[1] = f2bf(a.y); u.s[2] = f2bf(a.z); u.s[3] = f2bf(a.w);
            u.s[4] = f2bf(b.x); u.s[5] = f2bf(b.y); u.s[6] = f2bf(b.z); u.s[7] = f2bf(b.w);
        } else {
#pragma unroll
            for (int q = 0; q < 8; q++) u.s[q] = 0;
        }
        int byte = (row * 256 + cb * 16) ^ ((row & 7) << 4);
        *(bf16x8*)&Xl[byte] = u.v;
    }
    __syncthreads();
    int w = t >> 6, l = t & 63;
    int lrow = l & 15, lq = l >> 4;
    int r0 = (w & 1) * 64, c0 = (w >> 1) * 64;
    f32x4 acc[4][4];
#pragma unroll
    for (int i = 0; i < 4; i++)
#pragma unroll
        for (int j = 0; j < 4; j++) acc[i][j] = (f32x4){0.f, 0.f, 0.f, 0.f};
#pragma unroll
    for (int ks = 0; ks < 4; ks++) {
        int k0 = ks * 32;
        bf16x8 af[4], bq[4];
#pragma unroll
        for (int i = 0; i < 4; i++) {
            int rr = r0 + i * 16 + lrow;
            int byte = (rr * 256 + k0 * 2 + lq * 16) ^ ((rr & 7) << 4);
            af[i] = *(const bf16x8*)&Xl[byte];
        }
#pragma unroll
        for (int j = 0; j < 4; j++) {
            int j16 = (c0 >> 4) + j;
            bq[j] = *(const bf16x8*)&Wpk[(((size_t)ks * 8 + j16) * 64 + l) * 8];
        }
#pragma unroll
        for (int i = 0; i < 4; i++)
#pragma unroll
            for (int j = 0; j < 4; j++)
                acc[i][j] = __builtin_amdgcn_mfma_f32_16x16x32_bf16(af[i], bq[j], acc[i][j], 0, 0, 0);
    }
#pragma unroll
    for (int i = 0; i < 4; i++) {
#pragma unroll
        for (int j = 0; j < 4; j++) {
#pragma unroll
            for (int q = 0; q < 4; q++) {
                int n = nb0 + r0 + i * 16 + lq * 4 + q;
                if (n < NN) Ybf[(size_t)n * DD + c0 + j * 16 + lrow] = f2bf(acc[i][j][q]);
            }
        }
    }
}

// ---------------- s_src/s_dst from bf16 xh ----------------
__global__ void ssd_k(const unsigned short* __restrict__ xh_bf, const float* __restrict__ a_src,
                      const float* __restrict__ a_dst, float* __restrict__ s_src,
                      float* __restrict__ s_dst) {
    __shared__ float as[128], ad[128];
    if (threadIdx.x < 128) {
        as[threadIdx.x] = a_src[threadIdx.x];
        ad[threadIdx.x] = a_dst[threadIdx.x];
    }
    __syncthreads();
    int idx = blockIdx.x * 256 + threadIdx.x;
    if (idx >= NN * HH) return;
    int n = idx >> 3, h = idx & 7;
    const unsigned short* x = &xh_bf[(size_t)n * DD + h * CC];
    U8 u0, u1;
    u0.v = *(const bf16x8*)(x);
    u1.v = *(const bf16x8*)(x + 8);
    float s1 = 0.f, s2 = 0.f;
#pragma unroll
    for (int c = 0; c < 8; c++) {
        float v = bf2f(u0.s[c]);
        s1 += v * as[h * CC + c];
        s2 += v * ad[h * CC + c];
    }
#pragma unroll
    for (int c = 0; c < 8; c++) {
        float v = bf2f(u1.s[c]);
        s1 += v * as[h * CC + 8 + c];
        s2 += v * ad[h * CC + 8 + c];
    }
    s_src[idx] = s1;
    s_dst[idx] = s2;
}

// ---------------- fused aggregation + bias + LayerNorm + leaky + residual ----------------
__global__ __launch_bounds__(256) void agg_ln_k(const int* __restrict__ row_start,
                                                const int2* __restrict__ es_eid,
                                                const float* __restrict__ s_src,
                                                const float* __restrict__ s_dst,
                                                const float* __restrict__ s_e,
                                                const unsigned short* __restrict__ xh_bf,
                                                const float* __restrict__ bias,
                                                const float* __restrict__ g,
                                                const float* __restrict__ be,
                                                const float* __restrict__ res,
                                                float* __restrict__ outNf) {
    int wid = (blockIdx.x * 256 + threadIdx.x) >> 6;
    if (wid >= NN) return;
    int lane = threadIdx.x & 63;
    int h = lane >> 3;
    float sdst = s_dst[wid * 8 + h];
    int beg = row_start[wid], end = row_start[wid + 1];
    float acc0 = 0.f, acc1 = 0.f, z = 0.f;
    int p = beg;
    for (; p + 4 <= end; p += 4) {
        int q0 = es_eid[p].x;
        int q1 = es_eid[p + 1].x;
        int q2 = es_eid[p + 2].x;
        int q3 = es_eid[p + 3].x;
        float a0 = s_src[q0 * 8 + h] + sdst + s_e[(size_t)p * 8 + h];
        float a1 = s_src[q1 * 8 + h] + sdst + s_e[(size_t)(p + 1) * 8 + h];
        float a2 = s_src[q2 * 8 + h] + sdst + s_e[(size_t)(p + 2) * 8 + h];
        float a3 = s_src[q3 * 8 + h] + sdst + s_e[(size_t)(p + 3) * 8 + h];
        unsigned u0 = *(const unsigned*)&xh_bf[(size_t)q0 * DD + lane * 2];
        unsigned u1 = *(const unsigned*)&xh_bf[(size_t)q1 * DD + lane * 2];
        unsigned u2 = *(const unsigned*)&xh_bf[(size_t)q2 * DD + lane * 2];
        unsigned u3 = *(const unsigned*)&xh_bf[(size_t)q3 * DD + lane * 2];
        a0 = (a0 > 0.f) ? a0 : 0.2f * a0;
        a1 = (a1 > 0.f) ? a1 : 0.2f * a1;
        a2 = (a2 > 0.f) ? a2 : 0.2f * a2;
        a3 = (a3 > 0.f) ? a3 : 0.2f * a3;
        float e0 = __expf(a0);
        float e1 = __expf(a1);
        float e2 = __expf(a2);
        float e3 = __expf(a3);
        z += (e0 + e1) + (e2 + e3);
        acc0 = fmaf(e0, bf2f(u0 & 0xffffu), acc0);
        acc1 = fmaf(e0, bf2f(u0 >> 16), acc1);
        acc0 = fmaf(e1, bf2f(u1 & 0xffffu), acc0);
        acc1 = fmaf(e1, bf2f(u1 >> 16), acc1);
        acc0 = fmaf(e2, bf2f(u2 & 0xffffu), acc0);
        acc1 = fmaf(e2, bf2f(u2 >> 16), acc1);
        acc0 = fmaf(e3, bf2f(u3 & 0xffffu), acc0);
        acc1 = fmaf(e3, bf2f(u3 >> 16), acc1);
    }
    for (; p < end; p++) {
        int q0 = es_eid[p].x;
        float a0 = s_src[q0 * 8 + h] + sdst + s_e[(size_t)p * 8 + h];
        unsigned u0 = *(const unsigned*)&xh_bf[(size_t)q0 * DD + lane * 2];
        a0 = (a0 > 0.f) ? a0 : 0.2f * a0;
        float e0 = __expf(a0);
        z += e0;
        acc0 = fmaf(e0, bf2f(u0 & 0xffffu), acc0);
        acc1 = fmaf(e0, bf2f(u0 >> 16), acc1);
    }
    float inv = 1.f / (z + 1e-16f);
    float2 b = *(const float2*)&bias[lane * 2];
    float x0 = acc0 * inv + b.x;
    float x1 = acc1 * inv + b.y;
    float s = x0 + x1;
    float q = x0 * x0 + x1 * x1;
#pragma unroll
    for (int m = 1; m < 64; m <<= 1) {
        s += __shfl_xor(s, m, 64);
        q += __shfl_xor(q, m, 64);
    }
    float mu = s * (1.f / 128.f);
    float var = (q - 128.f * mu * mu) * (1.f / 127.f);
    float sd = sqrtf(fmaxf(var, 0.f));
    float invs = 1.f / (sd + 1e-6f);
    float2 gg = *(const float2*)&g[lane * 2];
    float2 bb = *(const float2*)&be[lane * 2];
    float y0 = gg.x * (x0 - mu) * invs + bb.x;
    float y1 = gg.y * (x1 - mu) * invs + bb.y;
    y0 = (y0 > 0.f) ? y0 : 0.01f * y0;
    y1 = (y1 > 0.f) ? y1 : 0.01f * y1;
    float2 r = *(const float2*)&res[(size_t)wid * DD + lane * 2];
    *(float2*)&outNf[(size_t)wid * DD + lane * 2] = make_float2(r.x + y0, r.y + y1);
}

// ---------------- bias + LayerNorm(ddof=1) + leaky_relu + residual ----------------
__global__ __launch_bounds__(256) void ln_k(const float* __restrict__ hin,
                                            const float* __restrict__ bias,
                                            const float* __restrict__ g,
                                            const float* __restrict__ be,
                                            const float* __restrict__ res,
                                            float* __restrict__ out) {
    int wid = (blockIdx.x * 256 + threadIdx.x) >> 6;
    if (wid >= NN) return;
    int lane = threadIdx.x & 63;
    float2 x = *(const float2*)&hin[(size_t)wid * DD + lane * 2];
    float2 b = *(const float2*)&bias[lane * 2];
    x.x += b.x;
    x.y += b.y;
    float s = x.x + x.y;
    float q = x.x * x.x + x.y * x.y;
#pragma unroll
    for (int m = 1; m < 64; m <<= 1) {
        s += __shfl_xor(s, m, 64);
        q += __shfl_xor(q, m, 64);
    }
    float mu = s * (1.f / 128.f);
    float var = (q - 128.f * mu * mu) * (1.f / 127.f);
    float sd = sqrtf(fmaxf(var, 0.f));
    float inv = 1.f / (sd + 1e-6f);
    float2 gg = *(const float2*)&g[lane * 2];
    float2 bb = *(const float2*)&be[lane * 2];
    float y0 = gg.x * (x.x - mu) * inv + bb.x;
    float y1 = gg.y * (x.y - mu) * inv + bb.y;
    y0 = (y0 > 0.f) ? y0 : 0.01f * y0;
    y1 = (y1 > 0.f) ? y1 : 0.01f * y1;
    float2 r = *(const float2*)&res[(size_t)wid * DD + lane * 2];
    *(float2*)&out[(size_t)wid * DD + lane * 2] = make_float2(r.x + y0, r.y + y1);
}

// ---------------- fused MFMA FFN: 64 nodes/block, hidden in 4 chunks of 128 ----------------
__global__ __launch_bounds__(256) void ffn_mfma_k(const float* __restrict__ X,
                                                  const unsigned short* __restrict__ Wf1pk,
                                                  const float* __restrict__ bf1,
                                                  const unsigned short* __restrict__ Wf2pk,
                                                  float* __restrict__ out) {
    __shared__ char Xl[64 * 256];   // bf16 [64][128] swizzled, 16KB
    __shared__ char Hl[64 * 256];   // bf16 [64][128] swizzled, 16KB
    int t = threadIdx.x;
    int nb0 = blockIdx.x * 64;
    for (int c = t; c < 1024; c += 256) {
        int row = c >> 4, cb = c & 15;
        int n = nb0 + row;
        U8 u;
        if (n < NN) {
            const float* xp = &X[(size_t)n * DD + cb * 8];
            float4 a = *(const float4*)xp;
            float4 b = *(const float4*)(xp + 4);
            u.s[0] = f2bf(a.x); u.s[1] = f2bf(a.y); u.s[2] = f2bf(a.z); u.s[3] = f2bf(a.w);
            u.s[4] = f2bf(b.x); u.s[5] = f2bf(b.y); u.s[6] = f2bf(b.z); u.s[7] = f2bf(b.w);
        } else {
#pragma unroll
            for (int q = 0; q < 8; q++) u.s[q] = 0;
        }
        int byte = (row * 256 + cb * 16) ^ ((row & 7) << 4);
        *(bf16x8*)&Xl[byte] = u.v;
    }
    __syncthreads();
    int w = t >> 6, l = t & 63;
    int lrow = l & 15, lq = l >> 4;
    int wr = (w & 1) * 32;
    int wc = (w >> 1) * 64;
    f32x4 oacc[2][4];
#pragma unroll
    for (int i = 0; i < 2; i++)
#pragma unroll
        for (int j = 0; j < 4; j++) oacc[i][j] = (f32x4){0.f, 0.f, 0.f, 0.f};

#pragma unroll
    for (int ch = 0; ch < 4; ch++) {
        int hc0 = ch * 128;
        f32x4 a[2][4];
#pragma unroll
        for (int i = 0; i < 2; i++)
#pragma unroll
            for (int j = 0; j < 4; j++) a[i][j] = (f32x4){0.f, 0.f, 0.f, 0.f};
#pragma unroll
        for (int ks = 0; ks < 4; ks++) {
            int k0 = ks * 32;
            bf16x8 af[2], bq[4];
#pragma unroll
            for (int i = 0; i < 2; i++) {
                int rr = wr + i * 16 + lrow;
                int byte = (rr * 256 + k0 * 2 + lq * 16) ^ ((rr & 7) << 4);
                af[i] = *(const bf16x8*)&Xl[byte];
            }
#pragma unroll
            for (int j = 0; j < 4; j++) {
                int j16 = ch * 8 + (wc >> 4) + j;
                bq[j] = *(const bf16x8*)&Wf1pk[(((size_t)ks * 32 + j16) * 64 + l) * 8];
            }
#pragma unroll
            for (int i = 0; i < 2; i++)
#pragma unroll
                for (int j = 0; j < 4; j++)
                    a[i][j] = __builtin_amdgcn_mfma_f32_16x16x32_bf16(af[i], bq[j], a[i][j], 0, 0, 0);
        }
        float bias[4];
#pragma unroll
        for (int j = 0; j < 4; j++) bias[j] = bf1[hc0 + wc + j * 16 + lrow];
#pragma unroll
        for (int i = 0; i < 2; i++) {
#pragma unroll
            for (int j = 0; j < 4; j++) {
#pragma unroll
                for (int q = 0; q < 4; q++) {
                    float v = fmaxf(a[i][j][q] + bias[j], 0.f);
                    int row = wr + i * 16 + lq * 4 + q;
                    int col = wc + j * 16 + lrow;
                    int byte = (row * 256 + col * 2) ^ ((row & 7) << 4);
                    *(unsigned short*)&Hl[byte] = f2bf(v);
                }
            }
        }
        __syncthreads();
#pragma unroll
        for (int ks = 0; ks < 4; ks++) {
            int k0 = ks * 32;
            bf16x8 hf[2], b2[4];
#pragma unroll
            for (int i = 0; i < 2; i++) {
                int rr = wr + i * 16 + lrow;
                int byte = (rr * 256 + k0 * 2 + lq * 16) ^ ((rr & 7) << 4);
                hf[i] = *(const bf16x8*)&Hl[byte];
            }
#pragma unroll
            for (int j = 0; j < 4; j++) {
                int kt = ch * 4 + ks;
                int j16 = (wc >> 4) + j;
                b2[j] = *(const bf16x8*)&Wf2pk[(((size_t)kt * 8 + j16) * 64 + l) * 8];
            }
#pragma unroll
            for (int i = 0; i < 2; i++)
#pragma unroll
                for (int j = 0; j < 4; j++)
                    oacc[i][j] = __builtin_amdgcn_mfma_f32_16x16x32_bf16(hf[i], b2[j], oacc[i][j], 0, 0, 0);
        }
        __syncthreads();
    }
#pragma unroll
    for (int i = 0; i < 2; i++) {
#pragma unroll
        for (int j = 0; j < 4; j++) {
#pragma unroll
            for (int q = 0; q < 4; q++) {
                int n = nb0 + wr + i * 16 + lq * 4 + q;
                if (n < NN) out[(size_t)n * DD + wc + j * 16 + lrow] = oacc[i][j][q];
            }
        }
    }
}

extern "C" void kernel_launch(void* const* d_in, const int* in_sizes, int n_in,
                              void* d_out, int out_size, void* d_ws, size_t ws_size,
                              hipStream_t stream) {
    const float* nf  = (const float*)d_in[0];
    const int*   ei  = (const int*)d_in[1];
    const float* ew  = (const float*)d_in[2];
    const float* W1  = (const float*)d_in[3];
    const float* as1 = (const float*)d_in[4];
    const float* ad1 = (const float*)d_in[5];
    const float* We1 = (const float*)d_in[6];
    const float* ae1 = (const float*)d_in[7];
    const float* b1  = (const float*)d_in[8];
    const float* g1  = (const float*)d_in[9];
    const float* be1 = (const float*)d_in[10];
    const float* W2  = (const float*)d_in[11];
    const float* as2 = (const float*)d_in[12];
    const float* ad2 = (const float*)d_in[13];
    const float* We2 = (const float*)d_in[14];
    const float* ae2 = (const float*)d_in[15];
    const float* b2  = (const float*)d_in[16];
    const float* g2  = (const float*)d_in[17];
    const float* be2 = (const float*)d_in[18];
    const float* Wf1 = (const float*)d_in[19];
    const float* bf1 = (const float*)d_in[20];
    const float* Wf2 = (const float*)d_in[21];
    const float* bf2 = (const float*)d_in[22];
    const float* g3  = (const float*)d_in[23];
    const float* be3 = (const float*)d_in[24];
    float* out = (float*)d_out;

    char* p = (char*)d_ws;
    auto alloc = [&](size_t bytes) {
        char* r = p;
        p += (bytes + 255) & ~(size_t)255;
        return r;
    };
    float* nf_cur = (float*)alloc((size_t)NN * DD * 4);
    unsigned short* xh_bf = (unsigned short*)alloc((size_t)NN * DD * 2);
    float* s_e1   = (float*)alloc((size_t)NE * HH * 4);
    float* s_e2   = (float*)alloc((size_t)NE * HH * 4);
    float* s_src  = (float*)alloc((size_t)NN * HH * 4);
    float* s_dst  = (float*)alloc((size_t)NN * HH * 4);
    int* row_start = (int*)alloc((size_t)(NN + 1) * 4);
    int* cnt       = (int*)alloc((size_t)NN * 4);
    int* cursor    = (int*)alloc((size_t)NN * 4);
    int* partials  = (int*)alloc((size_t)SCAN_NB * 4);
    int* bucket_cursor = (int*)alloc((size_t)NBKT * 4);
    int2* binned   = (int2*)alloc((size_t)NE * 8);
    int2* es_eid   = (int2*)alloc((size_t)NE * 8);
    unsigned short* W1pk  = (unsigned short*)alloc((size_t)DD * DD * 2);
    unsigned short* W2pk  = (unsigned short*)alloc((size_t)DD * DD * 2);
    unsigned short* Wf1pk = (unsigned short*)alloc((size_t)DD * DFF * 2);
    unsigned short* Wf2pk = (unsigned short*)alloc((size_t)DFF * DD * 2);
    float* h_out = s_e1;   // alias: s_e1 dead after layer-2 agg; sizes equal (NE*8*4 == NN*128*4)

    int ebl = (NE + 255) / 256;
    int nbl = (NN + 255) / 256;

    // weight pack+cvt (tiny, once): fragment-order bf16
    cvtpack_k<<<(DD * DD + 255) / 256, 256, 0, stream>>>(W1, W1pk, DD, DD);
    cvtpack_k<<<(DD * DD + 255) / 256, 256, 0, stream>>>(W2, W2pk, DD, DD);
    cvtpack_k<<<(DD * DFF + 255) / 256, 256, 0, stream>>>(Wf1, Wf1pk, DD, DFF);
    cvtpack_k<<<(DD * DFF + 255) / 256, 256, 0, stream>>>(Wf2, Wf2pk, DFF, DD);

    // CSR build (hierarchical scan)
    zero_int_k<<<nbl, 256, 0, stream>>>(cnt, NN);
    count_k<<<ebl, 256, 0, stream>>>(ei + NE, cnt);
    blksum_k<<<SCAN_NB, 256, 0, stream>>>(cnt, partials);
    scanpart_k<<<1, 256, 0, stream>>>(partials);
    scanapply_k<<<SCAN_NB, 256, 0, stream>>>(cnt, partials, row_start, cursor);

    // two-level binned scatter (kills cross-XCD write amplification)
    bucketbase_k<<<(NBKT + 255) / 256, 256, 0, stream>>>(row_start, bucket_cursor);
    bin_k<<<(NE + EPB - 1) / EPB, 256, 0, stream>>>(ei, bucket_cursor, binned);
    csr_scatter_k<<<NBKT, 256, 0, stream>>>(binned, row_start, cursor, es_eid);

    // edge scores for BOTH layers, coalesced writes
    se2_k<<<ebl, 256, 0, stream>>>(ew, es_eid, We1, ae1, We2, ae2, s_e1, s_e2);

    int gbl = (NN + 127) / 128;
    int wbl = (NN + 3) / 4;
    int sbl = (NN * HH + 255) / 256;

    // ---- GAT layer 1 ----
    gemm_mfma_k<<<gbl, 256, 0, stream>>>(nf, W1pk, xh_bf);
    ssd_k<<<sbl, 256, 0, stream>>>(xh_bf, as1, ad1, s_src, s_dst);
    agg_ln_k<<<wbl, 256, 0, stream>>>(row_start, es_eid, s_src, s_dst, s_e1, xh_bf,
                                      b1, g1, be1, nf, nf_cur);

    // ---- GAT layer 2 ----
    gemm_mfma_k<<<gbl, 256, 0, stream>>>(nf_cur, W2pk, xh_bf);
    ssd_k<<<sbl, 256, 0, stream>>>(xh_bf, as2, ad2, s_src, s_dst);
    agg_ln_k<<<wbl, 256, 0, stream>>>(row_start, es_eid, s_src, s_dst, s_e2, xh_bf,
                                      b2, g2, be2, nf_cur, nf_cur);

    // ---- FFN ----
    ffn_mfma_k<<<(NN + 63) / 64, 256, 0, stream>>>(nf_cur, Wf1pk, bf1, Wf2pk, h_out);
    ln_k<<<wbl, 256, 0, stream>>>(h_out, bf2, g3, be3, nf_cur, out);
}

// Round 10
// 302.305 us; speedup vs baseline: 1.3747x; 1.0033x over previous
//
#include <hip/hip_runtime.h>
#include <hip/hip_bf16.h>

#define NN 50000
#define NE 800000
#define DD 128
#define HH 8
#define CC 16
#define DFF 512
#define ED 16
#define SCAN_NB ((NN + 255) / 256)   // 196
#define BKT 256
#define NBKT ((NN + BKT - 1) / BKT)  // 196
#define EPB 4096

typedef __attribute__((ext_vector_type(8))) short bf16x8;
typedef __attribute__((ext_vector_type(4))) float f32x4;

union U8 { bf16x8 v; unsigned short s[8]; };

__device__ inline unsigned short f2bf(float f) {
    union { float f; unsigned u; } v; v.f = f;
    return (unsigned short)((v.u + 0x7fffu + ((v.u >> 16) & 1u)) >> 16);
}
__device__ inline float bf2f(unsigned s) {
    union { unsigned u; float f; } v; v.u = s << 16;
    return v.f;
}

// ---------------- utility ----------------
__global__ void zero_int_k(int* __restrict__ a, int n) {
    int i = blockIdx.x * 256 + threadIdx.x;
    if (i < n) a[i] = 0;
}

// pack weights into MFMA B-fragment order
__global__ void cvtpack_k(const float* __restrict__ W, unsigned short* __restrict__ Wpk,
                          int K, int N) {
    int idx = blockIdx.x * 256 + threadIdx.x;
    if (idx >= K * N) return;
    int e = idx & 7;
    int l = (idx >> 3) & 63;
    int r = idx >> 9;
    int n16 = N >> 4;
    int jc = r % n16;
    int kt = r / n16;
    int k = kt * 32 + (l >> 4) * 8 + e;
    int n = jc * 16 + (l & 15);
    Wpk[idx] = f2bf(W[(size_t)k * N + n]);
}

// ---------------- CSR build ----------------
__global__ void count_k(const int* __restrict__ dst, int* __restrict__ cnt) {
    int e = blockIdx.x * 256 + threadIdx.x;
    if (e < NE) atomicAdd(&cnt[dst[e]], 1);
}

__global__ void blksum_k(const int* __restrict__ cnt, int* __restrict__ partials) {
    int i = blockIdx.x * 256 + threadIdx.x;
    int v = (i < NN) ? cnt[i] : 0;
#pragma unroll
    for (int m = 1; m < 64; m <<= 1) v += __shfl_xor(v, m, 64);
    __shared__ int ws[4];
    if ((threadIdx.x & 63) == 0) ws[threadIdx.x >> 6] = v;
    __syncthreads();
    if (threadIdx.x == 0) partials[blockIdx.x] = ws[0] + ws[1] + ws[2] + ws[3];
}

__global__ void scanpart_k(int* __restrict__ partials) {
    __shared__ int buf[256];
    int t = threadIdx.x;
    int v = (t < SCAN_NB) ? partials[t] : 0;
    buf[t] = v;
    __syncthreads();
    for (int off = 1; off < 256; off <<= 1) {
        int u = (t >= off) ? buf[t - off] : 0;
        __syncthreads();
        buf[t] += u;
        __syncthreads();
    }
    if (t < SCAN_NB) partials[t] = buf[t] - v;  // exclusive
}

__global__ void scanapply_k(const int* __restrict__ cnt, const int* __restrict__ partials,
                            int* __restrict__ row_start, int* __restrict__ cursor) {
    __shared__ int buf[256];
    int t = threadIdx.x;
    int i = blockIdx.x * 256 + t;
    int v = (i < NN) ? cnt[i] : 0;
    buf[t] = v;
    __syncthreads();
    for (int off = 1; off < 256; off <<= 1) {
        int u = (t >= off) ? buf[t - off] : 0;
        __syncthreads();
        buf[t] += u;
        __syncthreads();
    }
    int excl = buf[t] - v + partials[blockIdx.x];
    if (i < NN) {
        row_start[i] = excl;
        cursor[i] = excl;
        if (i == NN - 1) row_start[NN] = excl + v;
    }
}

__global__ void bucketbase_k(const int* __restrict__ row_start, int* __restrict__ bucket_cursor) {
    int b = blockIdx.x * 256 + threadIdx.x;
    if (b < NBKT) bucket_cursor[b] = row_start[b * BKT];
}

// pass A: bin edges into bucket-major order with LDS-chunked (burst) writes
__global__ __launch_bounds__(256) void bin_k(const int* __restrict__ ei,
                                             int* __restrict__ bucket_cursor,
                                             int2* __restrict__ binned) {
    __shared__ int hist[NBKT];
    __shared__ int base[NBKT];
    int t = threadIdx.x;
    int e0 = blockIdx.x * EPB;
    int eend = e0 + EPB; if (eend > NE) eend = NE;
    if (t < NBKT) hist[t] = 0;
    __syncthreads();
    for (int e = e0 + t; e < eend; e += 256) {
        int d = ei[NE + e];
        atomicAdd(&hist[d >> 8], 1);
    }
    __syncthreads();
    if (t < NBKT) {
        int c = hist[t];
        base[t] = c ? atomicAdd(&bucket_cursor[t], c) : 0;
        hist[t] = 0;   // reuse as local cursor
    }
    __syncthreads();
    for (int e = e0 + t; e < eend; e += 256) {
        int s = ei[e];
        int d = ei[NE + e];
        int b = d >> 8;
        int loc = atomicAdd(&hist[b], 1);
        binned[base[b] + loc] = make_int2(s | ((d & 255) << 16), e);
    }
}

// pass B: per-bucket CSR scatter (SoA outputs: e_src for agg, e_eid for se2)
__global__ __launch_bounds__(256) void csr_scatter_k(const int2* __restrict__ binned,
                                                     const int* __restrict__ row_start,
                                                     int* __restrict__ cursor,
                                                     int* __restrict__ e_src,
                                                     int* __restrict__ e_eid) {
    int b = blockIdx.x;
    int beg = row_start[b * BKT];
    int endNode = (b + 1) * BKT; if (endNode > NN) endNode = NN;
    int end = row_start[endNode];
    for (int p = beg + threadIdx.x; p < end; p += 256) {
        int2 r = binned[p];
        int d = b * BKT + (r.x >> 16);
        int pos = atomicAdd(&cursor[d], 1);
        e_src[pos] = r.x & 0xffff;
        e_eid[pos] = r.y;
    }
}

// ---------------- edge scores, both layers, CSR order ----------------
__global__ void se2_k(const float* __restrict__ ew, const int* __restrict__ e_eid,
                      const float* __restrict__ We1, const float* __restrict__ ae1,
                      const float* __restrict__ We2, const float* __restrict__ ae2,
                      float* __restrict__ s_e1, float* __restrict__ s_e2) {
    __shared__ float A1[ED * HH], A2[ED * HH];
    int t = threadIdx.x;
    if (t < 128) {
        int k = t >> 3, h = t & 7;
        float s = 0.f;
#pragma unroll
        for (int c = 0; c < CC; c++) s += We1[k * DD + h * CC + c] * ae1[h * CC + c];
        A1[t] = s;
    } else {
        int u = t - 128;
        int k = u >> 3, h = u & 7;
        float s = 0.f;
#pragma unroll
        for (int c = 0; c < CC; c++) s += We2[k * DD + h * CC + c] * ae2[h * CC + c];
        A2[u] = s;
    }
    __syncthreads();
    int p = blockIdx.x * 256 + t;
    if (p >= NE) return;
    int eid = e_eid[p];
    const float* ep = &ew[(size_t)eid * ED];
    float4 v0 = *(const float4*)(ep);
    float4 v1 = *(const float4*)(ep + 4);
    float4 v2 = *(const float4*)(ep + 8);
    float4 v3 = *(const float4*)(ep + 12);
    float ev[16] = {v0.x, v0.y, v0.z, v0.w, v1.x, v1.y, v1.z, v1.w,
                    v2.x, v2.y, v2.z, v2.w, v3.x, v3.y, v3.z, v3.w};
    float o1[8] = {0, 0, 0, 0, 0, 0, 0, 0};
    float o2[8] = {0, 0, 0, 0, 0, 0, 0, 0};
#pragma unroll
    for (int k = 0; k < 16; k++) {
        float v = ev[k];
#pragma unroll
        for (int h = 0; h < 8; h++) {
            o1[h] += v * A1[k * 8 + h];
            o2[h] += v * A2[k * 8 + h];
        }
    }
    *(float4*)&s_e1[(size_t)p * 8]     = make_float4(o1[0], o1[1], o1[2], o1[3]);
    *(float4*)&s_e1[(size_t)p * 8 + 4] = make_float4(o1[4], o1[5], o1[6], o1[7]);
    *(float4*)&s_e2[(size_t)p * 8]     = make_float4(o2[0], o2[1], o2[2], o2[3]);
    *(float4*)&s_e2[(size_t)p * 8 + 4] = make_float4(o2[4], o2[5], o2[6], o2[7]);
}

// ---------------- MFMA node GEMM: Ybf = bf16(X @ W), W packed in fragment order ----------------
__global__ __launch_bounds__(256) void gemm_mfma_k(const float* __restrict__ X,
                                                   const unsigned short* __restrict__ Wpk,
                                                   unsigned short* __restrict__ Ybf) {
    __shared__ char Xl[128 * 256];  // bf16 [row][128], XOR-swizzled
    int t = threadIdx.x;
    int nb0 = blockIdx.x * 128;
    for (int c = t; c < 2048; c += 256) {
        int row = c >> 4, cb = c & 15;
        int n = nb0 + row;
        U8 u;
        if (n < NN) {
            const float* xp = &X[(size_t)n * DD + cb * 8];
            float4 a = *(const float4*)xp;
            float4 b = *(const float4*)(xp + 4);
            u.s[0] = f2bf(a.x); u.s[1] = f2bf(a.y); u.s[2] = f2bf(a.z); u.s[3] = f2bf(a.w);
            u.s[4] = f2bf(b.x); u.s[5] = f2bf(b.y); u.s[6] = f2bf(b.z); u.s[7] = f2bf(b.w);
        } else {
#pragma unroll
            for (int q = 0; q < 8; q++) u.s[q] = 0;
        }
        int byte = (row * 256 + cb * 16) ^ ((row & 7) << 4);
        *(bf16x8*)&Xl[byte] = u.v;
    }
    __syncthreads();
    int w = t >> 6, l = t & 63;
    int lrow = l & 15, lq = l >> 4;
    int r0 = (w & 1) * 64, c0 = (w >> 1) * 64;
    f32x4 acc[4][4];
#pragma unroll
    for (int i = 0; i < 4; i++)
#pragma unroll
        for (int j = 0; j < 4; j++) acc[i][j] = (f32x4){0.f, 0.f, 0.f, 0.f};
#pragma unroll
    for (int ks = 0; ks < 4; ks++) {
        int k0 = ks * 32;
        bf16x8 af[4], bq[4];
#pragma unroll
        for (int i = 0; i < 4; i++) {
            int rr = r0 + i * 16 + lrow;
            int byte = (rr * 256 + k0 * 2 + lq * 16) ^ ((rr & 7) << 4);
            af[i] = *(const bf16x8*)&Xl[byte];
        }
#pragma unroll
        for (int j = 0; j < 4; j++) {
            int j16 = (c0 >> 4) + j;
            bq[j] = *(const bf16x8*)&Wpk[(((size_t)ks * 8 + j16) * 64 + l) * 8];
        }
#pragma unroll
        for (int i = 0; i < 4; i++)
#pragma unroll
            for (int j = 0; j < 4; j++)
                acc[i][j] = __builtin_amdgcn_mfma_f32_16x16x32_bf16(af[i], bq[j], acc[i][j], 0, 0, 0);
    }
#pragma unroll
    for (int i = 0; i < 4; i++) {
#pragma unroll
        for (int j = 0; j < 4; j++) {
#pragma unroll
            for (int q = 0; q < 4; q++) {
                int n = nb0 + r0 + i * 16 + lq * 4 + q;
                if (n < NN) Ybf[(size_t)n * DD + c0 + j * 16 + lrow] = f2bf(acc[i][j][q]);
            }
        }
    }
}

// ---------------- s_src/s_dst from bf16 xh ----------------
__global__ void ssd_k(const unsigned short* __restrict__ xh_bf, const float* __restrict__ a_src,
                      const float* __restrict__ a_dst, float* __restrict__ s_src,
                      float* __restrict__ s_dst) {
    __shared__ float as[128], ad[128];
    if (threadIdx.x < 128) {
        as[threadIdx.x] = a_src[threadIdx.x];
        ad[threadIdx.x] = a_dst[threadIdx.x];
    }
    __syncthreads();
    int idx = blockIdx.x * 256 + threadIdx.x;
    if (idx >= NN * HH) return;
    int n = idx >> 3, h = idx & 7;
    const unsigned short* x = &xh_bf[(size_t)n * DD + h * CC];
    U8 u0, u1;
    u0.v = *(const bf16x8*)(x);
    u1.v = *(const bf16x8*)(x + 8);
    float s1 = 0.f, s2 = 0.f;
#pragma unroll
    for (int c = 0; c < 8; c++) {
        float v = bf2f(u0.s[c]);
        s1 += v * as[h * CC + c];
        s2 += v * ad[h * CC + c];
    }
#pragma unroll
    for (int c = 0; c < 8; c++) {
        float v = bf2f(u1.s[c]);
        s1 += v * as[h * CC + 8 + c];
        s2 += v * ad[h * CC + 8 + c];
    }
    s_src[idx] = s1;
    s_dst[idx] = s2;
}

// ---------------- fused aggregation + bias + LayerNorm + leaky + residual ----------------
// 32-bit byte-offset addressing on all gather streams
__global__ __launch_bounds__(256) void agg_ln_k(const int* __restrict__ row_start,
                                                const int* __restrict__ e_src,
                                                const float* __restrict__ s_src,
                                                const float* __restrict__ s_dst,
                                                const float* __restrict__ s_e,
                                                const unsigned short* __restrict__ xh_bf,
                                                const float* __restrict__ bias,
                                                const float* __restrict__ g,
                                                const float* __restrict__ be,
                                                const float* __restrict__ res,
                                                float* __restrict__ outNf) {
    int wid = (blockIdx.x * 256 + threadIdx.x) >> 6;
    if (wid >= NN) return;
    int lane = threadIdx.x & 63;
    int h = lane >> 3;
    unsigned hoff = (unsigned)h << 2;
    unsigned loff = (unsigned)lane << 2;
    const char* xb = (const char*)xh_bf;
    const char* sb = (const char*)s_src;
    const char* eb = (const char*)s_e;
    float sdst = s_dst[wid * 8 + h];
    int beg = row_start[wid], end = row_start[wid + 1];
    float acc0 = 0.f, acc1 = 0.f, z = 0.f;
    int p = beg;
    for (; p + 4 <= end; p += 4) {
        unsigned q0 = (unsigned)e_src[p];
        unsigned q1 = (unsigned)e_src[p + 1];
        unsigned q2 = (unsigned)e_src[p + 2];
        unsigned q3 = (unsigned)e_src[p + 3];
        float a0 = *(const float*)(sb + (q0 << 5) + hoff) + sdst + *(const float*)(eb + ((unsigned)p << 5) + hoff);
        float a1 = *(const float*)(sb + (q1 << 5) + hoff) + sdst + *(const float*)(eb + ((unsigned)(p + 1) << 5) + hoff);
        float a2 = *(const float*)(sb + (q2 << 5) + hoff) + sdst + *(const float*)(eb + ((unsigned)(p + 2) << 5) + hoff);
        float a3 = *(const float*)(sb + (q3 << 5) + hoff) + sdst + *(const float*)(eb + ((unsigned)(p + 3) << 5) + hoff);
        unsigned u0 = *(const unsigned*)(xb + (q0 << 8) + loff);
        unsigned u1 = *(const unsigned*)(xb + (q1 << 8) + loff);
        unsigned u2 = *(const unsigned*)(xb + (q2 << 8) + loff);
        unsigned u3 = *(const unsigned*)(xb + (q3 << 8) + loff);
        a0 = (a0 > 0.f) ? a0 : 0.2f * a0;
        a1 = (a1 > 0.f) ? a1 : 0.2f * a1;
        a2 = (a2 > 0.f) ? a2 : 0.2f * a2;
        a3 = (a3 > 0.f) ? a3 : 0.2f * a3;
        float e0 = __expf(a0);
        float e1 = __expf(a1);
        float e2 = __expf(a2);
        float e3 = __expf(a3);
        z += (e0 + e1) + (e2 + e3);
        acc0 = fmaf(e0, bf2f(u0 & 0xffffu), acc0);
        acc1 = fmaf(e0, bf2f(u0 >> 16), acc1);
        acc0 = fmaf(e1, bf2f(u1 & 0xffffu), acc0);
        acc1 = fmaf(e1, bf2f(u1 >> 16), acc1);
        acc0 = fmaf(e2, bf2f(u2 & 0xffffu), acc0);
        acc1 = fmaf(e2, bf2f(u2 >> 16), acc1);
        acc0 = fmaf(e3, bf2f(u3 & 0xffffu), acc0);
        acc1 = fmaf(e3, bf2f(u3 >> 16), acc1);
    }
    for (; p < end; p++) {
        unsigned q0 = (unsigned)e_src[p];
        float a0 = *(const float*)(sb + (q0 << 5) + hoff) + sdst + *(const float*)(eb + ((unsigned)p << 5) + hoff);
        unsigned u0 = *(const unsigned*)(xb + (q0 << 8) + loff);
        a0 = (a0 > 0.f) ? a0 : 0.2f * a0;
        float e0 = __expf(a0);
        z += e0;
        acc0 = fmaf(e0, bf2f(u0 & 0xffffu), acc0);
        acc1 = fmaf(e0, bf2f(u0 >> 16), acc1);
    }
    float inv = 1.f / (z + 1e-16f);
    float2 b = *(const float2*)&bias[lane * 2];
    float x0 = acc0 * inv + b.x;
    float x1 = acc1 * inv + b.y;
    float s = x0 + x1;
    float q = x0 * x0 + x1 * x1;
#pragma unroll
    for (int m = 1; m < 64; m <<= 1) {
        s += __shfl_xor(s, m, 64);
        q += __shfl_xor(q, m, 64);
    }
    float mu = s * (1.f / 128.f);
    float var = (q - 128.f * mu * mu) * (1.f / 127.f);
    float sd = sqrtf(fmaxf(var, 0.f));
    float invs = 1.f / (sd + 1e-6f);
    float2 gg = *(const float2*)&g[lane * 2];
    float2 bb = *(const float2*)&be[lane * 2];
    float y0 = gg.x * (x0 - mu) * invs + bb.x;
    float y1 = gg.y * (x1 - mu) * invs + bb.y;
    y0 = (y0 > 0.f) ? y0 : 0.01f * y0;
    y1 = (y1 > 0.f) ? y1 : 0.01f * y1;
    float2 r = *(const float2*)&res[(size_t)wid * DD + lane * 2];
    *(float2*)&outNf[(size_t)wid * DD + lane * 2] = make_float2(r.x + y0, r.y + y1);
}

// ---------------- bias + LayerNorm(ddof=1) + leaky_relu + residual ----------------
__global__ __launch_bounds__(256) void ln_k(const float* __restrict__ hin,
                                            const float* __restrict__ bias,
                                            const float* __restrict__ g,
                                            const float* __restrict__ be,
                                            const float* __restrict__ res,
                                            float* __restrict__ out) {
    int wid = (blockIdx.x * 256 + threadIdx.x) >> 6;
    if (wid >= NN) return;
    int lane = threadIdx.x & 63;
    float2 x = *(const float2*)&hin[(size_t)wid * DD + lane * 2];
    float2 b = *(const float2*)&bias[lane * 2];
    x.x += b.x;
    x.y += b.y;
    float s = x.x + x.y;
    float q = x.x * x.x + x.y * x.y;
#pragma unroll
    for (int m = 1; m < 64; m <<= 1) {
        s += __shfl_xor(s, m, 64);
        q += __shfl_xor(q, m, 64);
    }
    float mu = s * (1.f / 128.f);
    float var = (q - 128.f * mu * mu) * (1.f / 127.f);
    float sd = sqrtf(fmaxf(var, 0.f));
    float inv = 1.f / (sd + 1e-6f);
    float2 gg = *(const float2*)&g[lane * 2];
    float2 bb = *(const float2*)&be[lane * 2];
    float y0 = gg.x * (x.x - mu) * inv + bb.x;
    float y1 = gg.y * (x.y - mu) * inv + bb.y;
    y0 = (y0 > 0.f) ? y0 : 0.01f * y0;
    y1 = (y1 > 0.f) ? y1 : 0.01f * y1;
    float2 r = *(const float2*)&res[(size_t)wid * DD + lane * 2];
    *(float2*)&out[(size_t)wid * DD + lane * 2] = make_float2(r.x + y0, r.y + y1);
}

// ---------------- fused MFMA FFN: 64 nodes/block, hidden in 4 chunks of 128 ----------------
__global__ __launch_bounds__(256) void ffn_mfma_k(const float* __restrict__ X,
                                                  const unsigned short* __restrict__ Wf1pk,
                                                  const float* __restrict__ bf1,
                                                  const unsigned short* __restrict__ Wf2pk,
                                                  float* __restrict__ out) {
    __shared__ char Xl[64 * 256];   // bf16 [64][128] swizzled, 16KB
    __shared__ char Hl[64 * 256];   // bf16 [64][128] swizzled, 16KB
    int t = threadIdx.x;
    int nb0 = blockIdx.x * 64;
    for (int c = t; c < 1024; c += 256) {
        int row = c >> 4, cb = c & 15;
        int n = nb0 + row;
        U8 u;
        if (n < NN) {
            const float* xp = &X[(size_t)n * DD + cb * 8];
            float4 a = *(const float4*)xp;
            float4 b = *(const float4*)(xp + 4);
            u.s[0] = f2bf(a.x); u.s[1] = f2bf(a.y); u.s[2] = f2bf(a.z); u.s[3] = f2bf(a.w);
            u.s[4] = f2bf(b.x); u.s[5] = f2bf(b.y); u.s[6] = f2bf(b.z); u.s[7] = f2bf(b.w);
        } else {
#pragma unroll
            for (int q = 0; q < 8; q++) u.s[q] = 0;
        }
        int byte = (row * 256 + cb * 16) ^ ((row & 7) << 4);
        *(bf16x8*)&Xl[byte] = u.v;
    }
    __syncthreads();
    int w = t >> 6, l = t & 63;
    int lrow = l & 15, lq = l >> 4;
    int wr = (w & 1) * 32;
    int wc = (w >> 1) * 64;
    f32x4 oacc[2][4];
#pragma unroll
    for (int i = 0; i < 2; i++)
#pragma unroll
        for (int j = 0; j < 4; j++) oacc[i][j] = (f32x4){0.f, 0.f, 0.f, 0.f};

#pragma unroll
    for (int ch = 0; ch < 4; ch++) {
        int hc0 = ch * 128;
        f32x4 a[2][4];
#pragma unroll
        for (int i = 0; i < 2; i++)
#pragma unroll
            for (int j = 0; j < 4; j++) a[i][j] = (f32x4){0.f, 0.f, 0.f, 0.f};
#pragma unroll
        for (int ks = 0; ks < 4; ks++) {
            int k0 = ks * 32;
            bf16x8 af[2], bq[4];
#pragma unroll
            for (int i = 0; i < 2; i++) {
                int rr = wr + i * 16 + lrow;
                int byte = (rr * 256 + k0 * 2 + lq * 16) ^ ((rr & 7) << 4);
                af[i] = *(const bf16x8*)&Xl[byte];
            }
#pragma unroll
            for (int j = 0; j < 4; j++) {
                int j16 = ch * 8 + (wc >> 4) + j;
                bq[j] = *(const bf16x8*)&Wf1pk[(((size_t)ks * 32 + j16) * 64 + l) * 8];
            }
#pragma unroll
            for (int i = 0; i < 2; i++)
#pragma unroll
                for (int j = 0; j < 4; j++)
                    a[i][j] = __builtin_amdgcn_mfma_f32_16x16x32_bf16(af[i], bq[j], a[i][j], 0, 0, 0);
        }
        float bias[4];
#pragma unroll
        for (int j = 0; j < 4; j++) bias[j] = bf1[hc0 + wc + j * 16 + lrow];
#pragma unroll
        for (int i = 0; i < 2; i++) {
#pragma unroll
            for (int j = 0; j < 4; j++) {
#pragma unroll
                for (int q = 0; q < 4; q++) {
                    float v = fmaxf(a[i][j][q] + bias[j], 0.f);
                    int row = wr + i * 16 + lq * 4 + q;
                    int col = wc + j * 16 + lrow;
                    int byte = (row * 256 + col * 2) ^ ((row & 7) << 4);
                    *(unsigned short*)&Hl[byte] = f2bf(v);
                }
            }
        }
        __syncthreads();
#pragma unroll
        for (int ks = 0; ks < 4; ks++) {
            int k0 = ks * 32;
            bf16x8 hf[2], b2[4];
#pragma unroll
            for (int i = 0; i < 2; i++) {
                int rr = wr + i * 16 + lrow;
                int byte = (rr * 256 + k0 * 2 + lq * 16) ^ ((rr & 7) << 4);
                hf[i] = *(const bf16x8*)&Hl[byte];
            }
#pragma unroll
            for (int j = 0; j < 4; j++) {
                int kt = ch * 4 + ks;
                int j16 = (wc >> 4) + j;
                b2[j] = *(const bf16x8*)&Wf2pk[(((size_t)kt * 8 + j16) * 64 + l) * 8];
            }
#pragma unroll
            for (int i = 0; i < 2; i++)
#pragma unroll
                for (int j = 0; j < 4; j++)
                    oacc[i][j] = __builtin_amdgcn_mfma_f32_16x16x32_bf16(hf[i], b2[j], oacc[i][j], 0, 0, 0);
        }
        __syncthreads();
    }
#pragma unroll
    for (int i = 0; i < 2; i++) {
#pragma unroll
        for (int j = 0; j < 4; j++) {
#pragma unroll
            for (int q = 0; q < 4; q++) {
                int n = nb0 + wr + i * 16 + lq * 4 + q;
                if (n < NN) out[(size_t)n * DD + wc + j * 16 + lrow] = oacc[i][j][q];
            }
        }
    }
}

extern "C" void kernel_launch(void* const* d_in, const int* in_sizes, int n_in,
                              void* d_out, int out_size, void* d_ws, size_t ws_size,
                              hipStream_t stream) {
    const float* nf  = (const float*)d_in[0];
    const int*   ei  = (const int*)d_in[1];
    const float* ew  = (const float*)d_in[2];
    const float* W1  = (const float*)d_in[3];
    const float* as1 = (const float*)d_in[4];
    const float* ad1 = (const float*)d_in[5];
    const float* We1 = (const float*)d_in[6];
    const float* ae1 = (const float*)d_in[7];
    const float* b1  = (const float*)d_in[8];
    const float* g1  = (const float*)d_in[9];
    const float* be1 = (const float*)d_in[10];
    const float* W2  = (const float*)d_in[11];
    const float* as2 = (const float*)d_in[12];
    const float* ad2 = (const float*)d_in[13];
    const float* We2 = (const float*)d_in[14];
    const float* ae2 = (const float*)d_in[15];
    const float* b2  = (const float*)d_in[16];
    const float* g2  = (const float*)d_in[17];
    const float* be2 = (const float*)d_in[18];
    const float* Wf1 = (const float*)d_in[19];
    const float* bf1 = (const float*)d_in[20];
    const float* Wf2 = (const float*)d_in[21];
    const float* bf2 = (const float*)d_in[22];
    const float* g3  = (const float*)d_in[23];
    const float* be3 = (const float*)d_in[24];
    float* out = (float*)d_out;

    char* p = (char*)d_ws;
    auto alloc = [&](size_t bytes) {
        char* r = p;
        p += (bytes + 255) & ~(size_t)255;
        return r;
    };
    float* nf_cur = (float*)alloc((size_t)NN * DD * 4);
    unsigned short* xh_bf = (unsigned short*)alloc((size_t)NN * DD * 2);
    float* s_e1   = (float*)alloc((size_t)NE * HH * 4);
    float* s_e2   = (float*)alloc((size_t)NE * HH * 4);
    float* s_src  = (float*)alloc((size_t)NN * HH * 4);
    float* s_dst  = (float*)alloc((size_t)NN * HH * 4);
    int* row_start = (int*)alloc((size_t)(NN + 1) * 4);
    int* cnt       = (int*)alloc((size_t)NN * 4);
    int* cursor    = (int*)alloc((size_t)NN * 4);
    int* partials  = (int*)alloc((size_t)SCAN_NB * 4);
    int* bucket_cursor = (int*)alloc((size_t)NBKT * 4);
    int2* binned   = (int2*)alloc((size_t)NE * 8);
    int* e_src     = (int*)alloc((size_t)NE * 4);
    int* e_eid     = (int*)alloc((size_t)NE * 4);
    unsigned short* W1pk  = (unsigned short*)alloc((size_t)DD * DD * 2);
    unsigned short* W2pk  = (unsigned short*)alloc((size_t)DD * DD * 2);
    unsigned short* Wf1pk = (unsigned short*)alloc((size_t)DD * DFF * 2);
    unsigned short* Wf2pk = (unsigned short*)alloc((size_t)DFF * DD * 2);
    float* h_out = s_e1;   // alias: s_e1 dead after layer-2 agg; sizes equal (NE*8*4 == NN*128*4)

    int ebl = (NE + 255) / 256;
    int nbl = (NN + 255) / 256;

    // weight pack+cvt (tiny, once): fragment-order bf16
    cvtpack_k<<<(DD * DD + 255) / 256, 256, 0, stream>>>(W1, W1pk, DD, DD);
    cvtpack_k<<<(DD * DD + 255) / 256, 256, 0, stream>>>(W2, W2pk, DD, DD);
    cvtpack_k<<<(DD * DFF + 255) / 256, 256, 0, stream>>>(Wf1, Wf1pk, DD, DFF);
    cvtpack_k<<<(DD * DFF + 255) / 256, 256, 0, stream>>>(Wf2, Wf2pk, DFF, DD);

    // CSR build (hierarchical scan)
    zero_int_k<<<nbl, 256, 0, stream>>>(cnt, NN);
    count_k<<<ebl, 256, 0, stream>>>(ei + NE, cnt);
    blksum_k<<<SCAN_NB, 256, 0, stream>>>(cnt, partials);
    scanpart_k<<<1, 256, 0, stream>>>(partials);
    scanapply_k<<<SCAN_NB, 256, 0, stream>>>(cnt, partials, row_start, cursor);

    // two-level binned scatter (kills cross-XCD write amplification)
    bucketbase_k<<<(NBKT + 255) / 256, 256, 0, stream>>>(row_start, bucket_cursor);
    bin_k<<<(NE + EPB - 1) / EPB, 256, 0, stream>>>(ei, bucket_cursor, binned);
    csr_scatter_k<<<NBKT, 256, 0, stream>>>(binned, row_start, cursor, e_src, e_eid);

    // edge scores for BOTH layers, coalesced writes
    se2_k<<<ebl, 256, 0, stream>>>(ew, e_eid, We1, ae1, We2, ae2, s_e1, s_e2);

    int gbl = (NN + 127) / 128;
    int wbl = (NN + 3) / 4;
    int sbl = (NN * HH + 255) / 256;

    // ---- GAT layer 1 ----
    gemm_mfma_k<<<gbl, 256, 0, stream>>>(nf, W1pk, xh_bf);
    ssd_k<<<sbl, 256, 0, stream>>>(xh_bf, as1, ad1, s_src, s_dst);
    agg_ln_k<<<wbl, 256, 0, stream>>>(row_start, e_src, s_src, s_dst, s_e1, xh_bf,
                                      b1, g1, be1, nf, nf_cur);

    // ---- GAT layer 2 ----
    gemm_mfma_k<<<gbl, 256, 0, stream>>>(nf_cur, W2pk, xh_bf);
    ssd_k<<<sbl, 256, 0, stream>>>(xh_bf, as2, ad2, s_src, s_dst);
    agg_ln_k<<<wbl, 256, 0, stream>>>(row_start, e_src, s_src, s_dst, s_e2, xh_bf,
                                      b2, g2, be2, nf_cur, nf_cur);

    // ---- FFN ----
    ffn_mfma_k<<<(NN + 63) / 64, 256, 0, stream>>>(nf_cur, Wf1pk, bf1, Wf2pk, h_out);
    ln_k<<<wbl, 256, 0, stream>>>(h_out, bf2, g3, be3, nf_cur, out);
}